// Round 2
// baseline (2066.441 us; speedup 1.0000x reference)
//
#include <hip/hip_runtime.h>
#include <hip/hip_bf16.h>
#include <math.h>

// R7: R6 + amdgpu_waves_per_eu(4,4). R6's launch_bounds(1024,1) let the
// allocator target 8 waves/EU -> 64 VGPRs -> accumulator spills (WRITE_SIZE
// 1.09->3.0 GB, dur flat despite 2x occupancy). Dynamic LDS (117.5 KB) caps
// us at 1 block/CU = 4 waves/EU anyway; pinning (4,4) restores the 128-VGPR
// budget. No other change vs R6.

#define LSEQ 17
#define RS 260   // R row stride (f32)
#define TS 264   // AC/T1 row stride (u16)
#define SS 520   // W5 row stride (u16)
#define NTHR 1024
#define NWAVE 16

typedef unsigned short u16;
typedef __attribute__((ext_vector_type(8))) short short8;
typedef __attribute__((ext_vector_type(4))) float f32x4;

__device__ __forceinline__ float b2f(u16 u) {
    union { unsigned int i; float f; } x; x.i = ((unsigned int)u) << 16; return x.f;
}
__device__ __forceinline__ u16 f2b(float f) {
    union { float f; unsigned int i; } x; x.f = f;
    unsigned int r = x.i + 0x7FFFu + ((x.i >> 16) & 1u);
    return (u16)(r >> 16);
}
__device__ __forceinline__ float gelu_t(float x) {
    float u = 1.5957691216057308f * (x + 0.044715f * x * x * x);
    return x / (1.0f + __expf(-u));
}
__device__ __forceinline__ float siluf(float x) { return x / (1.0f + __expf(-x)); }
__device__ __forceinline__ float softplusf(float x) {
    return (x > 20.0f) ? x : __logf(1.0f + __expf(x));
}

__device__ const int   ADJ_MASK[17] = {0x93,0x7,0xE,0xC,0x31,0x70,0x60,0x181,0x4B80,
                                       0x700,0x600,0x1900,0x3800,0x3000,0xC100,0x1C000,0x18000};
__device__ const float DEG[17]    = {4,3,3,2,3,3,2,3,5,3,2,3,3,2,3,3,2};
__device__ const int   HOPA[17]   = {0,1,4,7,2,5,8,3,6,9,11,14,10,12,15,13,16};
__device__ const int   GRAPHA[17] = {0,1,4,7,2,5,8,3,6,9,12,10,13,15,11,14,16};
__device__ const int   BPEI[17]   = {0,1,2,0,1,2,0,1,2,0,3,4,0,3,4,3,4};

// ws fragment offsets (elements, bf16)
#define OFF_GCN_W1   0
#define OFF_GCN_W2   131072
#define OFF_INPROJ   262144
#define OFF_OUTPROJ  524288
#define OFF_QKV      655360
#define OFF_ATTNPROJ 851968
#define OFF_MLP_W1   917504
#define OFF_MLP_W2   1179648
#define OFF_XPROJ    1441792

// dynamic LDS carve (bytes)
#define SM_R    0
#define SM_AC   35360
#define SM_T1   53312
#define SM_W5   71264
#define SM_SC   106624
#define SM_DBL  115872
#define SM_AH   119136
#define SMEM_BYTES 120320

struct Params {
    const float *x, *gcn_ln_g, *gcn_ln_b, *gcn_w1, *gcn_b1, *gcn_w2, *gcn_b2,
                *bp_embed, *ssm_ln_g, *ssm_ln_b, *in_proj_w, *conv_w, *conv_b,
                *x_proj_w, *dt_proj_w, *dt_proj_b, *A_log, *Dp, *out_proj_w,
                *ln1_g, *ln1_b, *qkv_w, *attn_proj_w, *attn_proj_b,
                *ln2_g, *ln2_b, *mlp_w1, *mlp_b1, *mlp_w2, *mlp_b2;
    const u16* wws;
    float* out;
};

// ---------------- weight prepack: fp32 [K][N] -> bf16 B-fragments ----------------
__global__ __launch_bounds__(256) void prepack(Params P) {
    const int gid = blockIdx.x * 256 + threadIdx.x;
    const int cnt[9]  = {16384,16384,32768,16384,24576,8192,32768,32768,2048};
    const int Ns [9]  = {512,256,1024,256,768,256,1024,256,24};
    const int NPs[9]  = {512,256,1024,256,768,256,1024,256,32};
    const int offs[9] = {OFF_GCN_W1,OFF_GCN_W2,OFF_INPROJ,OFF_OUTPROJ,OFF_QKV,
                         OFF_ATTNPROJ,OFF_MLP_W1,OFF_MLP_W2,OFF_XPROJ};
    int e = 0, base = 0;
    while (e < 9 && gid >= base + cnt[e]) { base += cnt[e]; ++e; }
    if (e >= 9) return;
    const float* W;
    switch (e) {
        case 0: W = P.gcn_w1; break;      case 1: W = P.gcn_w2; break;
        case 2: W = P.in_proj_w; break;   case 3: W = P.out_proj_w; break;
        case 4: W = P.qkv_w; break;       case 5: W = P.attn_proj_w; break;
        case 6: W = P.mlp_w1; break;      case 7: W = P.mlp_w2; break;
        default: W = P.x_proj_w; break;
    }
    const int local = gid - base;
    const int lane = local & 63, frag = local >> 6;
    const int NT = NPs[e] >> 4;
    const int nt = frag % NT, kc = frag / NT;
    const int n = nt * 16 + (lane & 15);
    const int kbase = kc * 32 + (lane >> 4) * 8;
    u16 v[8];
    #pragma unroll
    for (int j = 0; j < 8; ++j)
        v[j] = (n < Ns[e]) ? f2b(W[(size_t)(kbase + j) * Ns[e] + n]) : (u16)0;
    u16* dst = (u16*)P.wws + offs[e] + ((size_t)frag * 64 + lane) * 8;
    *(short8*)dst = *(short8*)v;
}

// ---------------- MFMA helpers: 3 M-tiles over 34 packed rows, 16 waves ----------------
template <int KT, int NT4>
__device__ __forceinline__ void mfmaAcc(f32x4 acc[3][NT4],
        const u16* __restrict__ act, int ldin,
        const u16* __restrict__ wbase, int NT, int nt0, int ntcnt, int kc0) {
    const int lane = threadIdx.x & 63, wv = threadIdx.x >> 6;
    const int m = lane & 15, quad = lane >> 4;
    const bool v2 = (m < 2);
    for (int kc = 0; kc < KT; ++kc) {
        const int ko = kc * 32 + quad * 8;
        short8 a0 = *(const short8*)(act + m * ldin + ko);
        short8 a1 = *(const short8*)(act + (16 + m) * ldin + ko);
        short8 a2 = {0,0,0,0,0,0,0,0};
        if (v2) a2 = *(const short8*)(act + (32 + m) * ldin + ko);
        #pragma unroll
        for (int i = 0; i < NT4; ++i) {
            const int ntl = wv + NWAVE * i;
            if (ntl < ntcnt) {
                const short8 b = *(const short8*)(wbase +
                    ((size_t)((kc0 + kc) * NT + nt0 + ntl) * 64 + lane) * 8);
                acc[0][i] = __builtin_amdgcn_mfma_f32_16x16x32_bf16(a0, b, acc[0][i], 0, 0, 0);
                acc[1][i] = __builtin_amdgcn_mfma_f32_16x16x32_bf16(a1, b, acc[1][i], 0, 0, 0);
                acc[2][i] = __builtin_amdgcn_mfma_f32_16x16x32_bf16(a2, b, acc[2][i], 0, 0, 0);
            }
        }
    }
}

// epi(rr, c_rel, val): rr in [0,34) packed row, c_rel relative to nt0*16.
template <int NT4, class Epi>
__device__ __forceinline__ void mfmaStore(f32x4 acc[3][NT4], int ntcnt, Epi epi) {
    const int lane = threadIdx.x & 63, wv = threadIdx.x >> 6;
    const int col0 = lane & 15, quad = lane >> 4;
    #pragma unroll
    for (int i = 0; i < NT4; ++i) {
        const int ntl = wv + NWAVE * i;
        if (ntl < ntcnt) {
            const int cb = ntl * 16 + col0;
            #pragma unroll
            for (int r = 0; r < 4; ++r) epi(quad * 4 + r, cb, acc[0][i][r]);
            #pragma unroll
            for (int r = 0; r < 4; ++r) epi(16 + quad * 4 + r, cb, acc[1][i][r]);
            if (quad == 0) {
                epi(32, cb, acc[2][i][0]);
                epi(33, cb, acc[2][i][1]);
            }
        }
    }
}

template <int KT, int NT4, class Epi>
__device__ __forceinline__ void gemmM(const u16* act, int ldin,
        const u16* wbase, int NT, int nt0, int ntcnt, Epi epi) {
    f32x4 acc[3][NT4];
    #pragma unroll
    for (int mt = 0; mt < 3; ++mt)
        #pragma unroll
        for (int i = 0; i < NT4; ++i) acc[mt][i] = (f32x4){0.f,0.f,0.f,0.f};
    mfmaAcc<KT, NT4>(acc, act, ldin, wbase, NT, nt0, ntcnt, 0);
    mfmaStore<NT4>(acc, ntcnt, epi);
}

// ---------------- main fused kernel: 2 elements per block ----------------
__global__ __attribute__((amdgpu_waves_per_eu(4, 4))) __launch_bounds__(NTHR)
void fused_block(Params P) {
    extern __shared__ __align__(16) char smem[];
    float* R   = (float*)(smem + SM_R);    // [34][260] f32
    u16*   AC  = (u16*)  (smem + SM_AC);   // [34][264]
    u16*   T1  = (u16*)  (smem + SM_T1);   // [34][264]
    u16*   W5  = (u16*)  (smem + SM_W5);   // [34][520]
    u16*   SC  = (u16*)  (smem + SM_SC);   // [16][289]
    float* Dbl = (float*)(smem + SM_DBL);  // [34][24]
    float* Ah  = (float*)(smem + SM_AH);   // [289]

    const int tid = threadIdx.x;
    const int lane = tid & 63, wv = tid >> 6;
    const float* __restrict__ xg = P.x + (size_t)blockIdx.x * (2 * LSEQ * 256);
    const u16* __restrict__ ws = P.wws;

    // x -> R (34 contiguous rows), non-temporal float4
    for (int i4 = tid; i4 < 34 * 64; i4 += NTHR) {
        int rr = i4 >> 6, d4 = (i4 & 63) * 4;
        f32x4 v = __builtin_nontemporal_load((const f32x4*)(xg + rr * 256 + d4));
        *(f32x4*)(R + rr * RS + d4) = v;
    }
    for (int i = tid; i < 289; i += NTHR) {
        int r = i / 17, c = i - r * 17;
        Ah[i] = ((ADJ_MASK[r] >> c) & 1) ? rsqrtf(DEG[r] * DEG[c]) : 0.f;
    }
    __syncthreads();

    auto ln34 = [&](auto ld, u16* dst, const float* g, const float* bb) {
        for (int rr = wv; rr < 34; rr += NWAVE) {
            float v[4], s = 0.f, s2 = 0.f;
            #pragma unroll
            for (int j = 0; j < 4; ++j) {
                v[j] = ld(rr, lane + 64 * j);
                s += v[j]; s2 += v[j] * v[j];
            }
            #pragma unroll
            for (int m = 1; m < 64; m <<= 1) {
                s  += __shfl_xor(s, m, 64);
                s2 += __shfl_xor(s2, m, 64);
            }
            float mean = s * (1.0f / 256.0f);
            float var  = s2 * (1.0f / 256.0f) - mean * mean;
            float rstd = rsqrtf(var + 1e-5f);
            #pragma unroll
            for (int j = 0; j < 4; ++j) {
                int d = lane + 64 * j;
                dst[rr * TS + d] = f2b((v[j] - mean) * rstd * g[d] + bb[d]);
            }
        }
    };
    // per-element graph conv, in place; width = 256 or 512
    auto gconvIP = [&](u16* buf, int stride, int width) {
        for (int u = tid; u < 2 * width; u += NTHR) {
            int e = u / width, d = u - e * width;
            u16* be = buf + e * LSEQ * stride;
            float col[17];
            #pragma unroll
            for (int j = 0; j < 17; ++j) col[j] = b2f(be[j * stride + d]);
            #pragma unroll
            for (int i = 0; i < 17; ++i) {
                float s = 0.f;
                #pragma unroll
                for (int j = 0; j < 17; ++j) s += Ah[i * 17 + j] * col[j];
                be[i * stride + d] = f2b(s);
            }
        }
    };

    // ---------------- GCN ----------------
    ln34([&](int rr, int d) { return R[rr * RS + d]; }, AC, P.gcn_ln_g, P.gcn_ln_b);
    __syncthreads();
    gconvIP(AC, TS, 256);
    __syncthreads();
    gemmM<8, 2>(AC, TS, ws + OFF_GCN_W1, 32, 0, 32,
        [&](int rr, int c, float v) { W5[rr * SS + c] = f2b(gelu_t(v + P.gcn_b1[c])); });
    __syncthreads();
    gconvIP(W5, SS, 512);
    __syncthreads();
    gemmM<16, 1>(W5, SS, ws + OFF_GCN_W2, 16, 0, 16,
        [&](int rr, int c, float v) { R[rr * RS + c] += v + P.gcn_b2[c]; });  // x_a
    __syncthreads();

    // ---------------- Mamba ----------------
    for (int i = tid; i < 34 * 256; i += NTHR) {
        int rr = i >> 8, d = i & 255;
        int e = (rr >= 17), l = rr - e * 17;
        AC[rr * TS + d] = f2b(R[(e * 17 + HOPA[l]) * RS + d] + P.bp_embed[BPEI[l] * 256 + d]);
    }
    __syncthreads();
    ln34([&](int rr, int d) { return b2f(AC[rr * TS + d]); }, T1, P.ssm_ln_g, P.ssm_ln_b);
    __syncthreads();
    // xm = silu(conv(in_proj[:, :512]))
    gemmM<8, 2>(T1, TS, ws + OFF_INPROJ, 64, 0, 32,
        [&](int rr, int c, float v) { W5[rr * SS + c] = f2b(siluf(v * P.conv_w[c] + P.conv_b[c])); });
    __syncthreads();
    // x_proj (N=24 padded to 32)
    gemmM<16, 1>(W5, SS, ws + OFF_XPROJ, 2, 0, 2,
        [&](int rr, int c, float v) { if (c < 24) Dbl[rr * 24 + c] = v; });
    __syncthreads();
    // selective scan: thread owns channel d of ONE element (1024 indep chains)
    {
        const int e = tid >> 9, d = tid & 511;
        const int rb = e * 17;
        float wdt[16];
        #pragma unroll
        for (int r = 0; r < 16; ++r) wdt[r] = P.dt_proj_w[r * 512 + d];
        const float dtb = P.dt_proj_b[d];
        float Ar[4];
        #pragma unroll
        for (int s = 0; s < 4; ++s) Ar[s] = -__expf(P.A_log[d * 4 + s]);
        const float Dpd = P.Dp[d];
        float h0 = 0.f, h1 = 0.f, h2 = 0.f, h3 = 0.f;
        for (int t = 0; t < LSEQ; ++t) {
            const float* Dv = Dbl + (rb + t) * 24;
            float a = dtb;
            #pragma unroll
            for (int r = 0; r < 16; ++r) a += Dv[r] * wdt[r];
            float dt_ = softplusf(a);
            float xm = b2f(W5[(rb + t) * SS + d]);
            float p = dt_ * xm;
            h0 = __expf(dt_ * Ar[0]) * h0 + p * Dv[16];
            h1 = __expf(dt_ * Ar[1]) * h1 + p * Dv[17];
            h2 = __expf(dt_ * Ar[2]) * h2 + p * Dv[18];
            h3 = __expf(dt_ * Ar[3]) * h3 + p * Dv[19];
            float y = h0 * Dv[20] + h1 * Dv[21] + h2 * Dv[22] + h3 * Dv[23] + Dpd * xm;
            W5[(rb + t) * SS + d] = f2b(y);
        }
    }
    __syncthreads();
    // z half of in_proj; gate y in place
    gemmM<8, 2>(T1, TS, ws + OFF_INPROJ, 64, 32, 32,
        [&](int rr, int c, float v) {
            float y = b2f(W5[rr * SS + c]);
            W5[rr * SS + c] = f2b(y * siluf(v));
        });
    __syncthreads();
    gemmM<16, 1>(W5, SS, ws + OFF_OUTPROJ, 16, 0, 16,
        [&](int rr, int c, float v) { AC[rr * TS + c] = f2b(v); });
    __syncthreads();
    // x_b = 2*x_a + scatter(mamba_out)
    for (int i = tid; i < 34 * 256; i += NTHR) {
        int rr = i >> 8, d = i & 255;
        int e = (rr >= 17), l = rr - e * 17;
        R[rr * RS + d] = 2.0f * R[rr * RS + d] + b2f(AC[(e * 17 + GRAPHA[l]) * TS + d]);
    }
    __syncthreads();

    // ---------------- Attention ----------------
    ln34([&](int rr, int d) { return R[rr * RS + d]; }, AC, P.ln1_g, P.ln1_b);
    __syncthreads();
    // QKV single pass: 48 N-tiles over 16 waves. abs col cc: <256 Q -> T1; else K|V -> W5
    gemmM<8, 3>(AC, TS, ws + OFF_QKV, 48, 0, 48,
        [&](int rr, int c, float v) {
            if (c < 256) T1[rr * TS + c] = f2b(v);
            else         W5[rr * SS + (c - 256)] = f2b(v);
        });
    __syncthreads();
    {
        const int unit = tid >> 6;             // (e,h): e = unit>>3, h = unit&7
        const int e = unit >> 3, h = unit & 7, p = tid & 63;
        const int rb = e * 17;
        for (int idx = p; idx < 289; idx += 64) {
            int i = idx / 17, j = idx - i * 17;
            float s = 0.f;
            #pragma unroll
            for (int d2 = 0; d2 < 32; ++d2)
                s += b2f(T1[(rb + i) * TS + h * 32 + d2]) * b2f(W5[(rb + j) * SS + h * 32 + d2]);
            SC[unit * 289 + i * 17 + j] = f2b(s * 0.17677669529663687f);
        }
    }
    __syncthreads();
    if (tid < 272) {
        u16* row = SC + tid * 17;
        float e[17], mx = -3.0e38f, sum = 0.f;
        #pragma unroll
        for (int j = 0; j < 17; ++j) mx = fmaxf(mx, b2f(row[j]));
        #pragma unroll
        for (int j = 0; j < 17; ++j) { e[j] = __expf(b2f(row[j]) - mx); sum += e[j]; }
        float inv = 1.0f / sum;
        #pragma unroll
        for (int j = 0; j < 17; ++j) row[j] = f2b(e[j] * inv);
    }
    __syncthreads();
    {
        const int unit = tid >> 6;
        const int e = unit >> 3, h = unit & 7, p = tid & 63;
        const int dd = p & 31, rb = e * 17;
        for (int i = (p >> 5); i < 17; i += 2) {
            float s = 0.f;
            #pragma unroll
            for (int j = 0; j < 17; ++j)
                s += b2f(SC[unit * 289 + i * 17 + j]) * b2f(W5[(rb + j) * SS + 256 + h * 32 + dd]);
            AC[(rb + i) * TS + h * 32 + dd] = f2b(s);  // o (ln1 out dead)
        }
    }
    __syncthreads();
    // o' = attn_proj(o) + bias
    gemmM<8, 1>(AC, TS, ws + OFF_ATTNPROJ, 16, 0, 16,
        [&](int rr, int c, float v) { T1[rr * TS + c] = f2b(v + P.attn_proj_b[c]); });
    __syncthreads();

    // ---------------- MLP + final ----------------
    ln34([&](int rr, int d) { return R[rr * RS + d] + b2f(T1[rr * TS + d]); },
         AC, P.ln2_g, P.ln2_b);
    __syncthreads();
    {
        f32x4 accO[3][1];
        #pragma unroll
        for (int mt = 0; mt < 3; ++mt) accO[mt][0] = (f32x4){0.f,0.f,0.f,0.f};
        #pragma unroll
        for (int half = 0; half < 2; ++half) {
            gemmM<8, 2>(AC, TS, ws + OFF_MLP_W1, 64, half * 32, 32,
                [&](int rr, int c, float v) {
                    W5[rr * SS + c] = f2b(gelu_t(v + P.mlp_b1[half * 512 + c]));
                });
            __syncthreads();
            mfmaAcc<16, 1>(accO, W5, SS, ws + OFF_MLP_W2, 16, 0, 16, half * 16);
            __syncthreads();  // W5 reused next half
        }
        float* outg = P.out + (size_t)blockIdx.x * (2 * LSEQ * 256);
        mfmaStore<1>(accO, 16, [&](int rr, int c, float v) {
            float r = v + P.mlp_b2[c] + 2.0f * R[rr * RS + c] + b2f(T1[rr * TS + c]);
            __builtin_nontemporal_store(r, outg + rr * 256 + c);
        });
    }
}

extern "C" void kernel_launch(void* const* d_in, const int* in_sizes, int n_in,
                              void* d_out, int out_size, void* d_ws, size_t ws_size,
                              hipStream_t stream) {
    (void)in_sizes; (void)n_in; (void)ws_size; (void)out_size;
    Params P;
    P.x           = (const float*)d_in[0];
    P.gcn_ln_g    = (const float*)d_in[1];
    P.gcn_ln_b    = (const float*)d_in[2];
    P.gcn_w1      = (const float*)d_in[3];
    P.gcn_b1      = (const float*)d_in[4];
    P.gcn_w2      = (const float*)d_in[5];
    P.gcn_b2      = (const float*)d_in[6];
    P.bp_embed    = (const float*)d_in[7];
    P.ssm_ln_g    = (const float*)d_in[8];
    P.ssm_ln_b    = (const float*)d_in[9];
    P.in_proj_w   = (const float*)d_in[10];
    P.conv_w      = (const float*)d_in[11];
    P.conv_b      = (const float*)d_in[12];
    P.x_proj_w    = (const float*)d_in[13];
    P.dt_proj_w   = (const float*)d_in[14];
    P.dt_proj_b   = (const float*)d_in[15];
    P.A_log       = (const float*)d_in[16];
    P.Dp          = (const float*)d_in[17];
    P.out_proj_w  = (const float*)d_in[18];
    P.ln1_g       = (const float*)d_in[19];
    P.ln1_b       = (const float*)d_in[20];
    P.qkv_w       = (const float*)d_in[21];
    P.attn_proj_w = (const float*)d_in[22];
    P.attn_proj_b = (const float*)d_in[23];
    P.ln2_g       = (const float*)d_in[24];
    P.ln2_b       = (const float*)d_in[25];
    P.mlp_w1      = (const float*)d_in[26];
    P.mlp_b1      = (const float*)d_in[27];
    P.mlp_w2      = (const float*)d_in[28];
    P.mlp_b2      = (const float*)d_in[29];
    P.wws         = (const u16*)d_ws;
    P.out         = (float*)d_out;
    static int smem_set = 0;
    if (!smem_set) {
        hipFuncSetAttribute(reinterpret_cast<const void*>(fused_block),
                            hipFuncAttributeMaxDynamicSharedMemorySize, SMEM_BYTES);
        smem_set = 1;
    }
    hipLaunchKernelGGL(prepack, dim3(712), dim3(256), 0, stream, P);
    hipLaunchKernelGGL(fused_block, dim3(2048), dim3(NTHR), SMEM_BYTES, stream, P);
}

// Round 4
// 1538.931 us; speedup vs baseline: 1.3428x; 1.3428x over previous
//
#include <hip/hip_runtime.h>
#include <hip/hip_bf16.h>
#include <math.h>

// R9 = R8 resubmit (round-3 bench died on container acquire, no kernel signal).
// 1 element per block, 512 threads (8 waves), LDS 60.7 KB -> 2 blocks/CU.
// R6/R7 showed 1024-thr workgroups get a 64-VGPR budget (allocator ignores
// waves_per_eu) -> accumulator spills (WRITE 3 GB). This keeps R5's proven
// 512-thr/128-VGPR compile profile and gets 4 waves/SIMD via 2 co-resident
// independent blocks, whose barrier stalls overlap. M=17 -> 2 M-tiles (16+1),
// row-16 tile lane-gated (m==0), garbage C rows discarded on store.

#define LSEQ 17
#define RS 260   // R row stride (f32)
#define TS 264   // AC/T1 row stride (u16)
#define SS 520   // W5 row stride (u16)
#define NTHR 512
#define NWAVE 8

typedef unsigned short u16;
typedef __attribute__((ext_vector_type(8))) short short8;
typedef __attribute__((ext_vector_type(4))) float f32x4;

__device__ __forceinline__ float b2f(u16 u) {
    union { unsigned int i; float f; } x; x.i = ((unsigned int)u) << 16; return x.f;
}
__device__ __forceinline__ u16 f2b(float f) {
    union { float f; unsigned int i; } x; x.f = f;
    unsigned int r = x.i + 0x7FFFu + ((x.i >> 16) & 1u);
    return (u16)(r >> 16);
}
__device__ __forceinline__ float gelu_t(float x) {
    float u = 1.5957691216057308f * (x + 0.044715f * x * x * x);
    return x / (1.0f + __expf(-u));
}
__device__ __forceinline__ float siluf(float x) { return x / (1.0f + __expf(-x)); }
__device__ __forceinline__ float softplusf(float x) {
    return (x > 20.0f) ? x : __logf(1.0f + __expf(x));
}

__device__ const int   ADJ_MASK[17] = {0x93,0x7,0xE,0xC,0x31,0x70,0x60,0x181,0x4B80,
                                       0x700,0x600,0x1900,0x3800,0x3000,0xC100,0x1C000,0x18000};
__device__ const float DEG[17]    = {4,3,3,2,3,3,2,3,5,3,2,3,3,2,3,3,2};
__device__ const int   HOPA[17]   = {0,1,4,7,2,5,8,3,6,9,11,14,10,12,15,13,16};
__device__ const int   GRAPHA[17] = {0,1,4,7,2,5,8,3,6,9,12,10,13,15,11,14,16};
__device__ const int   BPEI[17]   = {0,1,2,0,1,2,0,1,2,0,3,4,0,3,4,3,4};

// ws fragment offsets (elements, bf16)
#define OFF_GCN_W1   0
#define OFF_GCN_W2   131072
#define OFF_INPROJ   262144
#define OFF_OUTPROJ  524288
#define OFF_QKV      655360
#define OFF_ATTNPROJ 851968
#define OFF_MLP_W1   917504
#define OFF_MLP_W2   1179648
#define OFF_XPROJ    1441792

// dynamic LDS carve (bytes) — 1 element: 17 rows
#define SM_R    0        // [17][260] f32 = 17680
#define SM_AC   17680    // [17][264] u16 = 8976
#define SM_T1   26656    // [17][264] u16 = 8976
#define SM_W5   35632    // [17][520] u16 = 17680
#define SM_SC   53312    // [8][289]  u16 = 4624
#define SM_DBL  57936    // [17][24]  f32 = 1632
#define SM_AH   59568    // [289]     f32 = 1156
#define SMEM_BYTES 60736

struct Params {
    const float *x, *gcn_ln_g, *gcn_ln_b, *gcn_w1, *gcn_b1, *gcn_w2, *gcn_b2,
                *bp_embed, *ssm_ln_g, *ssm_ln_b, *in_proj_w, *conv_w, *conv_b,
                *x_proj_w, *dt_proj_w, *dt_proj_b, *A_log, *Dp, *out_proj_w,
                *ln1_g, *ln1_b, *qkv_w, *attn_proj_w, *attn_proj_b,
                *ln2_g, *ln2_b, *mlp_w1, *mlp_b1, *mlp_w2, *mlp_b2;
    const u16* wws;
    float* out;
};

// ---------------- weight prepack: fp32 [K][N] -> bf16 B-fragments ----------------
__global__ __launch_bounds__(256) void prepack(Params P) {
    const int gid = blockIdx.x * 256 + threadIdx.x;
    const int cnt[9]  = {16384,16384,32768,16384,24576,8192,32768,32768,2048};
    const int Ns [9]  = {512,256,1024,256,768,256,1024,256,24};
    const int NPs[9]  = {512,256,1024,256,768,256,1024,256,32};
    const int offs[9] = {OFF_GCN_W1,OFF_GCN_W2,OFF_INPROJ,OFF_OUTPROJ,OFF_QKV,
                         OFF_ATTNPROJ,OFF_MLP_W1,OFF_MLP_W2,OFF_XPROJ};
    int e = 0, base = 0;
    while (e < 9 && gid >= base + cnt[e]) { base += cnt[e]; ++e; }
    if (e >= 9) return;
    const float* W;
    switch (e) {
        case 0: W = P.gcn_w1; break;      case 1: W = P.gcn_w2; break;
        case 2: W = P.in_proj_w; break;   case 3: W = P.out_proj_w; break;
        case 4: W = P.qkv_w; break;       case 5: W = P.attn_proj_w; break;
        case 6: W = P.mlp_w1; break;      case 7: W = P.mlp_w2; break;
        default: W = P.x_proj_w; break;
    }
    const int local = gid - base;
    const int lane = local & 63, frag = local >> 6;
    const int NT = NPs[e] >> 4;
    const int nt = frag % NT, kc = frag / NT;
    const int n = nt * 16 + (lane & 15);
    const int kbase = kc * 32 + (lane >> 4) * 8;
    u16 v[8];
    #pragma unroll
    for (int j = 0; j < 8; ++j)
        v[j] = (n < Ns[e]) ? f2b(W[(size_t)(kbase + j) * Ns[e] + n]) : (u16)0;
    u16* dst = (u16*)P.wws + offs[e] + ((size_t)frag * 64 + lane) * 8;
    *(short8*)dst = *(short8*)v;
}

// ---------------- MFMA helpers: 2 M-tiles over 17 rows, 8 waves ----------------
template <int KT, int NT4>
__device__ __forceinline__ void mfmaAcc(f32x4 acc[2][NT4],
        const u16* __restrict__ act, int ldin,
        const u16* __restrict__ wbase, int NT, int nt0, int ntcnt, int kc0) {
    const int lane = threadIdx.x & 63, wv = threadIdx.x >> 6;
    const int m = lane & 15, quad = lane >> 4;
    const bool v1 = (m < 1);
    for (int kc = 0; kc < KT; ++kc) {
        const int ko = kc * 32 + quad * 8;
        short8 a0 = *(const short8*)(act + m * ldin + ko);
        short8 a1 = {0,0,0,0,0,0,0,0};
        if (v1) a1 = *(const short8*)(act + 16 * ldin + ko);
        #pragma unroll
        for (int i = 0; i < NT4; ++i) {
            const int ntl = wv + NWAVE * i;
            if (ntl < ntcnt) {
                const short8 b = *(const short8*)(wbase +
                    ((size_t)((kc0 + kc) * NT + nt0 + ntl) * 64 + lane) * 8);
                acc[0][i] = __builtin_amdgcn_mfma_f32_16x16x32_bf16(a0, b, acc[0][i], 0, 0, 0);
                acc[1][i] = __builtin_amdgcn_mfma_f32_16x16x32_bf16(a1, b, acc[1][i], 0, 0, 0);
            }
        }
    }
}

// epi(rr, c_rel, val): rr in [0,17) row, c_rel relative to nt0*16.
template <int NT4, class Epi>
__device__ __forceinline__ void mfmaStore(f32x4 acc[2][NT4], int ntcnt, Epi epi) {
    const int lane = threadIdx.x & 63, wv = threadIdx.x >> 6;
    const int col0 = lane & 15, quad = lane >> 4;
    #pragma unroll
    for (int i = 0; i < NT4; ++i) {
        const int ntl = wv + NWAVE * i;
        if (ntl < ntcnt) {
            const int cb = ntl * 16 + col0;
            #pragma unroll
            for (int r = 0; r < 4; ++r) epi(quad * 4 + r, cb, acc[0][i][r]);
            if (quad == 0) epi(16, cb, acc[1][i][0]);
        }
    }
}

template <int KT, int NT4, class Epi>
__device__ __forceinline__ void gemmM(const u16* act, int ldin,
        const u16* wbase, int NT, int nt0, int ntcnt, Epi epi) {
    f32x4 acc[2][NT4];
    #pragma unroll
    for (int mt = 0; mt < 2; ++mt)
        #pragma unroll
        for (int i = 0; i < NT4; ++i) acc[mt][i] = (f32x4){0.f,0.f,0.f,0.f};
    mfmaAcc<KT, NT4>(acc, act, ldin, wbase, NT, nt0, ntcnt, 0);
    mfmaStore<NT4>(acc, ntcnt, epi);
}

// ---------------- main fused kernel: 1 element per block ----------------
__global__ __launch_bounds__(NTHR, 1) void fused_block(Params P) {
    extern __shared__ __align__(16) char smem[];
    float* R   = (float*)(smem + SM_R);    // [17][260] f32
    u16*   AC  = (u16*)  (smem + SM_AC);   // [17][264]
    u16*   T1  = (u16*)  (smem + SM_T1);   // [17][264]
    u16*   W5  = (u16*)  (smem + SM_W5);   // [17][520]
    u16*   SC  = (u16*)  (smem + SM_SC);   // [8][289]
    float* Dbl = (float*)(smem + SM_DBL);  // [17][24]
    float* Ah  = (float*)(smem + SM_AH);   // [289]

    const int tid = threadIdx.x;
    const int lane = tid & 63, wv = tid >> 6;
    const float* __restrict__ xg = P.x + (size_t)blockIdx.x * (LSEQ * 256);
    const u16* __restrict__ ws = P.wws;

    // x -> R (17 rows), non-temporal float4
    for (int i4 = tid; i4 < 17 * 64; i4 += NTHR) {
        int rr = i4 >> 6, d4 = (i4 & 63) * 4;
        f32x4 v = __builtin_nontemporal_load((const f32x4*)(xg + rr * 256 + d4));
        *(f32x4*)(R + rr * RS + d4) = v;
    }
    for (int i = tid; i < 289; i += NTHR) {
        int r = i / 17, c = i - r * 17;
        Ah[i] = ((ADJ_MASK[r] >> c) & 1) ? rsqrtf(DEG[r] * DEG[c]) : 0.f;
    }
    __syncthreads();

    auto ln17 = [&](auto ld, u16* dst, const float* g, const float* bb) {
        for (int rr = wv; rr < 17; rr += NWAVE) {
            float v[4], s = 0.f, s2 = 0.f;
            #pragma unroll
            for (int j = 0; j < 4; ++j) {
                v[j] = ld(rr, lane + 64 * j);
                s += v[j]; s2 += v[j] * v[j];
            }
            #pragma unroll
            for (int m = 1; m < 64; m <<= 1) {
                s  += __shfl_xor(s, m, 64);
                s2 += __shfl_xor(s2, m, 64);
            }
            float mean = s * (1.0f / 256.0f);
            float var  = s2 * (1.0f / 256.0f) - mean * mean;
            float rstd = rsqrtf(var + 1e-5f);
            #pragma unroll
            for (int j = 0; j < 4; ++j) {
                int d = lane + 64 * j;
                dst[rr * TS + d] = f2b((v[j] - mean) * rstd * g[d] + bb[d]);
            }
        }
    };
    // graph conv, in place; thread owns a full column (race-free)
    auto gconvIP = [&](u16* buf, int stride, int width) {
        if (tid < width) {
            const int d = tid;
            float col[17];
            #pragma unroll
            for (int j = 0; j < 17; ++j) col[j] = b2f(buf[j * stride + d]);
            #pragma unroll
            for (int i = 0; i < 17; ++i) {
                float s = 0.f;
                #pragma unroll
                for (int j = 0; j < 17; ++j) s += Ah[i * 17 + j] * col[j];
                buf[i * stride + d] = f2b(s);
            }
        }
    };

    // ---------------- GCN ----------------
    ln17([&](int rr, int d) { return R[rr * RS + d]; }, AC, P.gcn_ln_g, P.gcn_ln_b);
    __syncthreads();
    gconvIP(AC, TS, 256);
    __syncthreads();
    gemmM<8, 4>(AC, TS, ws + OFF_GCN_W1, 32, 0, 32,
        [&](int rr, int c, float v) { W5[rr * SS + c] = f2b(gelu_t(v + P.gcn_b1[c])); });
    __syncthreads();
    gconvIP(W5, SS, 512);
    __syncthreads();
    gemmM<16, 2>(W5, SS, ws + OFF_GCN_W2, 16, 0, 16,
        [&](int rr, int c, float v) { R[rr * RS + c] += v + P.gcn_b2[c]; });  // x_a
    __syncthreads();

    // ---------------- Mamba ----------------
    for (int i = tid; i < 17 * 256; i += NTHR) {
        int rr = i >> 8, d = i & 255;
        AC[rr * TS + d] = f2b(R[HOPA[rr] * RS + d] + P.bp_embed[BPEI[rr] * 256 + d]);
    }
    __syncthreads();
    ln17([&](int rr, int d) { return b2f(AC[rr * TS + d]); }, T1, P.ssm_ln_g, P.ssm_ln_b);
    __syncthreads();
    // xm = silu(conv(in_proj[:, :512]))
    gemmM<8, 4>(T1, TS, ws + OFF_INPROJ, 64, 0, 32,
        [&](int rr, int c, float v) { W5[rr * SS + c] = f2b(siluf(v * P.conv_w[c] + P.conv_b[c])); });
    __syncthreads();
    // x_proj (N=24 padded to 32)
    gemmM<16, 1>(W5, SS, ws + OFF_XPROJ, 2, 0, 2,
        [&](int rr, int c, float v) { if (c < 24) Dbl[rr * 24 + c] = v; });
    __syncthreads();
    // selective scan: thread owns channel d (512 indep chains)
    {
        const int d = tid;
        float wdt[16];
        #pragma unroll
        for (int r = 0; r < 16; ++r) wdt[r] = P.dt_proj_w[r * 512 + d];
        const float dtb = P.dt_proj_b[d];
        float Ar[4];
        #pragma unroll
        for (int s = 0; s < 4; ++s) Ar[s] = -__expf(P.A_log[d * 4 + s]);
        const float Dpd = P.Dp[d];
        float h0 = 0.f, h1 = 0.f, h2 = 0.f, h3 = 0.f;
        for (int t = 0; t < LSEQ; ++t) {
            const float* Dv = Dbl + t * 24;
            float a = dtb;
            #pragma unroll
            for (int r = 0; r < 16; ++r) a += Dv[r] * wdt[r];
            float dt_ = softplusf(a);
            float xm = b2f(W5[t * SS + d]);
            float p = dt_ * xm;
            h0 = __expf(dt_ * Ar[0]) * h0 + p * Dv[16];
            h1 = __expf(dt_ * Ar[1]) * h1 + p * Dv[17];
            h2 = __expf(dt_ * Ar[2]) * h2 + p * Dv[18];
            h3 = __expf(dt_ * Ar[3]) * h3 + p * Dv[19];
            float y = h0 * Dv[20] + h1 * Dv[21] + h2 * Dv[22] + h3 * Dv[23] + Dpd * xm;
            W5[t * SS + d] = f2b(y);
        }
    }
    __syncthreads();
    // z half of in_proj; gate y in place
    gemmM<8, 4>(T1, TS, ws + OFF_INPROJ, 64, 32, 32,
        [&](int rr, int c, float v) {
            float y = b2f(W5[rr * SS + c]);
            W5[rr * SS + c] = f2b(y * siluf(v));
        });
    __syncthreads();
    gemmM<16, 2>(W5, SS, ws + OFF_OUTPROJ, 16, 0, 16,
        [&](int rr, int c, float v) { AC[rr * TS + c] = f2b(v); });
    __syncthreads();
    // x_b = 2*x_a + scatter(mamba_out)
    for (int i = tid; i < 17 * 256; i += NTHR) {
        int rr = i >> 8, d = i & 255;
        R[rr * RS + d] = 2.0f * R[rr * RS + d] + b2f(AC[GRAPHA[rr] * TS + d]);
    }
    __syncthreads();

    // ---------------- Attention ----------------
    ln17([&](int rr, int d) { return R[rr * RS + d]; }, AC, P.ln1_g, P.ln1_b);
    __syncthreads();
    // QKV in two passes (tiles 0-23, 24-47). abs col cc: <256 Q -> T1; else K|V -> W5
    gemmM<8, 3>(AC, TS, ws + OFF_QKV, 48, 0, 24,
        [&](int rr, int c, float v) {
            if (c < 256) T1[rr * TS + c] = f2b(v);
            else         W5[rr * SS + (c - 256)] = f2b(v);
        });
    gemmM<8, 3>(AC, TS, ws + OFF_QKV, 48, 24, 24,
        [&](int rr, int c, float v) {
            W5[rr * SS + (c + 128)] = f2b(v);  // cc = c+384 -> W5 col cc-256
        });
    __syncthreads();
    {
        const int h = wv, p = tid & 63;       // 8 heads, 64 threads each
        for (int idx = p; idx < 289; idx += 64) {
            int i = idx / 17, j = idx - i * 17;
            float s = 0.f;
            #pragma unroll
            for (int d2 = 0; d2 < 32; ++d2)
                s += b2f(T1[i * TS + h * 32 + d2]) * b2f(W5[j * SS + h * 32 + d2]);
            SC[h * 289 + i * 17 + j] = f2b(s * 0.17677669529663687f);
        }
    }
    __syncthreads();
    if (tid < 136) {
        u16* row = SC + tid * 17;
        float e[17], mx = -3.0e38f, sum = 0.f;
        #pragma unroll
        for (int j = 0; j < 17; ++j) mx = fmaxf(mx, b2f(row[j]));
        #pragma unroll
        for (int j = 0; j < 17; ++j) { e[j] = __expf(b2f(row[j]) - mx); sum += e[j]; }
        float inv = 1.0f / sum;
        #pragma unroll
        for (int j = 0; j < 17; ++j) row[j] = f2b(e[j] * inv);
    }
    __syncthreads();
    {
        const int h = wv, p = tid & 63;
        const int dd = p & 31;
        for (int i = (p >> 5); i < 17; i += 2) {
            float s = 0.f;
            #pragma unroll
            for (int j = 0; j < 17; ++j)
                s += b2f(SC[h * 289 + i * 17 + j]) * b2f(W5[j * SS + 256 + h * 32 + dd]);
            AC[i * TS + h * 32 + dd] = f2b(s);  // o (ln1 out dead)
        }
    }
    __syncthreads();
    // o' = attn_proj(o) + bias
    gemmM<8, 2>(AC, TS, ws + OFF_ATTNPROJ, 16, 0, 16,
        [&](int rr, int c, float v) { T1[rr * TS + c] = f2b(v + P.attn_proj_b[c]); });
    __syncthreads();

    // ---------------- MLP + final ----------------
    ln17([&](int rr, int d) { return R[rr * RS + d] + b2f(T1[rr * TS + d]); },
         AC, P.ln2_g, P.ln2_b);
    __syncthreads();
    {
        f32x4 accO[2][2];
        #pragma unroll
        for (int mt = 0; mt < 2; ++mt)
            #pragma unroll
            for (int i = 0; i < 2; ++i) accO[mt][i] = (f32x4){0.f,0.f,0.f,0.f};
        #pragma unroll
        for (int half = 0; half < 2; ++half) {
            gemmM<8, 4>(AC, TS, ws + OFF_MLP_W1, 64, half * 32, 32,
                [&](int rr, int c, float v) {
                    W5[rr * SS + c] = f2b(gelu_t(v + P.mlp_b1[half * 512 + c]));
                });
            __syncthreads();
            mfmaAcc<16, 2>(accO, W5, SS, ws + OFF_MLP_W2, 16, 0, 16, half * 16);
            __syncthreads();  // W5 reused next half
        }
        float* outg = P.out + (size_t)blockIdx.x * (LSEQ * 256);
        mfmaStore<2>(accO, 16, [&](int rr, int c, float v) {
            float r = v + P.mlp_b2[c] + 2.0f * R[rr * RS + c] + b2f(T1[rr * TS + c]);
            __builtin_nontemporal_store(r, outg + rr * 256 + c);
        });
    }
}

extern "C" void kernel_launch(void* const* d_in, const int* in_sizes, int n_in,
                              void* d_out, int out_size, void* d_ws, size_t ws_size,
                              hipStream_t stream) {
    (void)in_sizes; (void)n_in; (void)ws_size; (void)out_size;
    Params P;
    P.x           = (const float*)d_in[0];
    P.gcn_ln_g    = (const float*)d_in[1];
    P.gcn_ln_b    = (const float*)d_in[2];
    P.gcn_w1      = (const float*)d_in[3];
    P.gcn_b1      = (const float*)d_in[4];
    P.gcn_w2      = (const float*)d_in[5];
    P.gcn_b2      = (const float*)d_in[6];
    P.bp_embed    = (const float*)d_in[7];
    P.ssm_ln_g    = (const float*)d_in[8];
    P.ssm_ln_b    = (const float*)d_in[9];
    P.in_proj_w   = (const float*)d_in[10];
    P.conv_w      = (const float*)d_in[11];
    P.conv_b      = (const float*)d_in[12];
    P.x_proj_w    = (const float*)d_in[13];
    P.dt_proj_w   = (const float*)d_in[14];
    P.dt_proj_b   = (const float*)d_in[15];
    P.A_log       = (const float*)d_in[16];
    P.Dp          = (const float*)d_in[17];
    P.out_proj_w  = (const float*)d_in[18];
    P.ln1_g       = (const float*)d_in[19];
    P.ln1_b       = (const float*)d_in[20];
    P.qkv_w       = (const float*)d_in[21];
    P.attn_proj_w = (const float*)d_in[22];
    P.attn_proj_b = (const float*)d_in[23];
    P.ln2_g       = (const float*)d_in[24];
    P.ln2_b       = (const float*)d_in[25];
    P.mlp_w1      = (const float*)d_in[26];
    P.mlp_b1      = (const float*)d_in[27];
    P.mlp_w2      = (const float*)d_in[28];
    P.mlp_b2      = (const float*)d_in[29];
    P.wws         = (const u16*)d_ws;
    P.out         = (float*)d_out;
    static int smem_set = 0;
    if (!smem_set) {
        hipFuncSetAttribute(reinterpret_cast<const void*>(fused_block),
                            hipFuncAttributeMaxDynamicSharedMemorySize, SMEM_BYTES);
        smem_set = 1;
    }
    hipLaunchKernelGGL(prepack, dim3(712), dim3(256), 0, stream, P);
    hipLaunchKernelGGL(fused_block, dim3(4096), dim3(NTHR), SMEM_BYTES, stream, P);
}

// Round 5
// 1343.311 us; speedup vs baseline: 1.5383x; 1.1456x over previous
//
#include <hip/hip_runtime.h>
#include <hip/hip_bf16.h>
#include <math.h>

// R10: R9 + (1) attention QK^T/AV via MFMA (wave=head), SC zero-padded [8][17][40]
// bf16 so AV K-padding is exact zeros, V B-frags k<17-masked; (2) sparse gconv:
// 49 compile-time-weight FMAs instead of dense 17x17 + LDS Ah (deleted);
// (3) SC unioned with Dbl, RS 260->256. LDS 62.4 KB, 512 thr, 1 elem/block.
// R9 counters: FETCH 47MB/WRITE 93MB (clean), occupancy 23.7% (1 blk/CU),
// VALU 32.5 / MFMA 10.7 -> latency-bound; this cuts the biggest VALU chains.

#define LSEQ 17
#define RS 256   // R row stride (f32)
#define TS 264   // AC/T1 row stride (u16)
#define SS 520   // W5 row stride (u16)
#define SCS 40   // SC row stride (u16)
#define NTHR 512
#define NWAVE 8

typedef unsigned short u16;
typedef __attribute__((ext_vector_type(8))) short short8;
typedef __attribute__((ext_vector_type(4))) float f32x4;

__device__ __forceinline__ float b2f(u16 u) {
    union { unsigned int i; float f; } x; x.i = ((unsigned int)u) << 16; return x.f;
}
__device__ __forceinline__ u16 f2b(float f) {
    union { float f; unsigned int i; } x; x.f = f;
    unsigned int r = x.i + 0x7FFFu + ((x.i >> 16) & 1u);
    return (u16)(r >> 16);
}
__device__ __forceinline__ float gelu_t(float x) {
    float u = 1.5957691216057308f * (x + 0.044715f * x * x * x);
    return x / (1.0f + __expf(-u));
}
__device__ __forceinline__ float siluf(float x) { return x / (1.0f + __expf(-x)); }
__device__ __forceinline__ float softplusf(float x) {
    return (x > 20.0f) ? x : __logf(1.0f + __expf(x));
}

__device__ const int HOPA[17]   = {0,1,4,7,2,5,8,3,6,9,11,14,10,12,15,13,16};
__device__ const int GRAPHA[17] = {0,1,4,7,2,5,8,3,6,9,12,10,13,15,11,14,16};
__device__ const int BPEI[17]   = {0,1,2,0,1,2,0,1,2,0,3,4,0,3,4,3,4};

// ws fragment offsets (elements, bf16)
#define OFF_GCN_W1   0
#define OFF_GCN_W2   131072
#define OFF_INPROJ   262144
#define OFF_OUTPROJ  524288
#define OFF_QKV      655360
#define OFF_ATTNPROJ 851968
#define OFF_MLP_W1   917504
#define OFF_MLP_W2   1179648
#define OFF_XPROJ    1441792

// dynamic LDS carve (bytes) — 1 element: 17 rows
#define SM_R    0        // [17][256] f32 = 17408
#define SM_AC   17408    // [17][264] u16 = 8976
#define SM_T1   26384    // [17][264] u16 = 8976
#define SM_W5   35360    // [17][520] u16 = 17680
#define SM_U    53040    // union: Dbl [17][24] f32 (1632) | SC [8][17][40] u16 (10880)
#define SMEM_BYTES 63920

struct Params {
    const float *x, *gcn_ln_g, *gcn_ln_b, *gcn_w1, *gcn_b1, *gcn_w2, *gcn_b2,
                *bp_embed, *ssm_ln_g, *ssm_ln_b, *in_proj_w, *conv_w, *conv_b,
                *x_proj_w, *dt_proj_w, *dt_proj_b, *A_log, *Dp, *out_proj_w,
                *ln1_g, *ln1_b, *qkv_w, *attn_proj_w, *attn_proj_b,
                *ln2_g, *ln2_b, *mlp_w1, *mlp_b1, *mlp_w2, *mlp_b2;
    const u16* wws;
    float* out;
};

// ---------------- weight prepack: fp32 [K][N] -> bf16 B-fragments ----------------
__global__ __launch_bounds__(256) void prepack(Params P) {
    const int gid = blockIdx.x * 256 + threadIdx.x;
    const int cnt[9]  = {16384,16384,32768,16384,24576,8192,32768,32768,2048};
    const int Ns [9]  = {512,256,1024,256,768,256,1024,256,24};
    const int NPs[9]  = {512,256,1024,256,768,256,1024,256,32};
    const int offs[9] = {OFF_GCN_W1,OFF_GCN_W2,OFF_INPROJ,OFF_OUTPROJ,OFF_QKV,
                         OFF_ATTNPROJ,OFF_MLP_W1,OFF_MLP_W2,OFF_XPROJ};
    int e = 0, base = 0;
    while (e < 9 && gid >= base + cnt[e]) { base += cnt[e]; ++e; }
    if (e >= 9) return;
    const float* W;
    switch (e) {
        case 0: W = P.gcn_w1; break;      case 1: W = P.gcn_w2; break;
        case 2: W = P.in_proj_w; break;   case 3: W = P.out_proj_w; break;
        case 4: W = P.qkv_w; break;       case 5: W = P.attn_proj_w; break;
        case 6: W = P.mlp_w1; break;      case 7: W = P.mlp_w2; break;
        default: W = P.x_proj_w; break;
    }
    const int local = gid - base;
    const int lane = local & 63, frag = local >> 6;
    const int NT = NPs[e] >> 4;
    const int nt = frag % NT, kc = frag / NT;
    const int n = nt * 16 + (lane & 15);
    const int kbase = kc * 32 + (lane >> 4) * 8;
    u16 v[8];
    #pragma unroll
    for (int j = 0; j < 8; ++j)
        v[j] = (n < Ns[e]) ? f2b(W[(size_t)(kbase + j) * Ns[e] + n]) : (u16)0;
    u16* dst = (u16*)P.wws + offs[e] + ((size_t)frag * 64 + lane) * 8;
    *(short8*)dst = *(short8*)v;
}

// ---------------- MFMA helpers: 2 M-tiles over 17 rows, 8 waves ----------------
template <int KT, int NT4>
__device__ __forceinline__ void mfmaAcc(f32x4 acc[2][NT4],
        const u16* __restrict__ act, int ldin,
        const u16* __restrict__ wbase, int NT, int nt0, int ntcnt, int kc0) {
    const int lane = threadIdx.x & 63, wv = threadIdx.x >> 6;
    const int m = lane & 15, quad = lane >> 4;
    const bool v1 = (m < 1);
    for (int kc = 0; kc < KT; ++kc) {
        const int ko = kc * 32 + quad * 8;
        short8 a0 = *(const short8*)(act + m * ldin + ko);
        short8 a1 = {0,0,0,0,0,0,0,0};
        if (v1) a1 = *(const short8*)(act + 16 * ldin + ko);
        #pragma unroll
        for (int i = 0; i < NT4; ++i) {
            const int ntl = wv + NWAVE * i;
            if (ntl < ntcnt) {
                const short8 b = *(const short8*)(wbase +
                    ((size_t)((kc0 + kc) * NT + nt0 + ntl) * 64 + lane) * 8);
                acc[0][i] = __builtin_amdgcn_mfma_f32_16x16x32_bf16(a0, b, acc[0][i], 0, 0, 0);
                acc[1][i] = __builtin_amdgcn_mfma_f32_16x16x32_bf16(a1, b, acc[1][i], 0, 0, 0);
            }
        }
    }
}

// epi(rr, c_rel, val): rr in [0,17) row, c_rel relative to nt0*16.
template <int NT4, class Epi>
__device__ __forceinline__ void mfmaStore(f32x4 acc[2][NT4], int ntcnt, Epi epi) {
    const int lane = threadIdx.x & 63, wv = threadIdx.x >> 6;
    const int col0 = lane & 15, quad = lane >> 4;
    #pragma unroll
    for (int i = 0; i < NT4; ++i) {
        const int ntl = wv + NWAVE * i;
        if (ntl < ntcnt) {
            const int cb = ntl * 16 + col0;
            #pragma unroll
            for (int r = 0; r < 4; ++r) epi(quad * 4 + r, cb, acc[0][i][r]);
            if (quad == 0) epi(16, cb, acc[1][i][0]);
        }
    }
}

template <int KT, int NT4, class Epi>
__device__ __forceinline__ void gemmM(const u16* act, int ldin,
        const u16* wbase, int NT, int nt0, int ntcnt, Epi epi) {
    f32x4 acc[2][NT4];
    #pragma unroll
    for (int mt = 0; mt < 2; ++mt)
        #pragma unroll
        for (int i = 0; i < NT4; ++i) acc[mt][i] = (f32x4){0.f,0.f,0.f,0.f};
    mfmaAcc<KT, NT4>(acc, act, ldin, wbase, NT, nt0, ntcnt, 0);
    mfmaStore<NT4>(acc, ntcnt, epi);
}

// ---------------- main fused kernel: 1 element per block ----------------
__global__ __launch_bounds__(NTHR, 1) void fused_block(Params P) {
    extern __shared__ __align__(16) char smem[];
    float* R   = (float*)(smem + SM_R);    // [17][256] f32
    u16*   AC  = (u16*)  (smem + SM_AC);   // [17][264]
    u16*   T1  = (u16*)  (smem + SM_T1);   // [17][264]
    u16*   W5  = (u16*)  (smem + SM_W5);   // [17][520]
    float* Dbl = (float*)(smem + SM_U);    // [17][24] (mamba only)
    u16*   SC  = (u16*)  (smem + SM_U);    // [8][17][40] (attention only)

    const int tid = threadIdx.x;
    const int lane = tid & 63, wv = tid >> 6;
    const float* __restrict__ xg = P.x + (size_t)blockIdx.x * (LSEQ * 256);
    const u16* __restrict__ ws = P.wws;

    // x -> R (17 rows), non-temporal float4
    for (int i4 = tid; i4 < 17 * 64; i4 += NTHR) {
        int rr = i4 >> 6, d4 = (i4 & 63) * 4;
        f32x4 v = __builtin_nontemporal_load((const f32x4*)(xg + rr * 256 + d4));
        *(f32x4*)(R + rr * RS + d4) = v;
    }
    __syncthreads();

    auto ln17 = [&](auto ld, u16* dst, const float* g, const float* bb) {
        for (int rr = wv; rr < 17; rr += NWAVE) {
            float v[4], s = 0.f, s2 = 0.f;
            #pragma unroll
            for (int j = 0; j < 4; ++j) {
                v[j] = ld(rr, lane + 64 * j);
                s += v[j]; s2 += v[j] * v[j];
            }
            #pragma unroll
            for (int m = 1; m < 64; m <<= 1) {
                s  += __shfl_xor(s, m, 64);
                s2 += __shfl_xor(s2, m, 64);
            }
            float mean = s * (1.0f / 256.0f);
            float var  = s2 * (1.0f / 256.0f) - mean * mean;
            float rstd = rsqrtf(var + 1e-5f);
            #pragma unroll
            for (int j = 0; j < 4; ++j) {
                int d = lane + 64 * j;
                dst[rr * TS + d] = f2b((v[j] - mean) * rstd * g[d] + bb[d]);
            }
        }
    };
    // sparse graph conv (49 nonzeros, compile-time weights), in place;
    // thread owns a full column (race-free)
    auto gconvIP = [&](u16* buf, int stride, int width) {
        if (tid < width) {
            const int d = tid;
            float c[17];
            #pragma unroll
            for (int j = 0; j < 17; ++j) c[j] = b2f(buf[j * stride + d]);
            float o[17];
            o[0]  = 0.25f*c[0] + 0.28867513f*(c[1]+c[4]+c[7]);
            o[1]  = 0.28867513f*c[0] + 0.33333334f*(c[1]+c[2]);
            o[2]  = 0.33333334f*(c[1]+c[2]) + 0.40824829f*c[3];
            o[3]  = 0.40824829f*c[2] + 0.5f*c[3];
            o[4]  = 0.28867513f*c[0] + 0.33333334f*(c[4]+c[5]);
            o[5]  = 0.33333334f*(c[4]+c[5]) + 0.40824829f*c[6];
            o[6]  = 0.40824829f*c[5] + 0.5f*c[6];
            o[7]  = 0.28867513f*c[0] + 0.33333334f*c[7] + 0.25819889f*c[8];
            o[8]  = 0.25819889f*(c[7]+c[9]+c[11]+c[14]) + 0.2f*c[8];
            o[9]  = 0.25819889f*c[8] + 0.33333334f*c[9] + 0.40824829f*c[10];
            o[10] = 0.40824829f*c[9] + 0.5f*c[10];
            o[11] = 0.25819889f*c[8] + 0.33333334f*(c[11]+c[12]);
            o[12] = 0.33333334f*(c[11]+c[12]) + 0.40824829f*c[13];
            o[13] = 0.40824829f*c[12] + 0.5f*c[13];
            o[14] = 0.25819889f*c[8] + 0.33333334f*(c[14]+c[15]);
            o[15] = 0.33333334f*(c[14]+c[15]) + 0.40824829f*c[16];
            o[16] = 0.40824829f*c[15] + 0.5f*c[16];
            #pragma unroll
            for (int i = 0; i < 17; ++i) buf[i * stride + d] = f2b(o[i]);
        }
    };

    // ---------------- GCN ----------------
    ln17([&](int rr, int d) { return R[rr * RS + d]; }, AC, P.gcn_ln_g, P.gcn_ln_b);
    __syncthreads();
    gconvIP(AC, TS, 256);
    __syncthreads();
    gemmM<8, 4>(AC, TS, ws + OFF_GCN_W1, 32, 0, 32,
        [&](int rr, int c, float v) { W5[rr * SS + c] = f2b(gelu_t(v + P.gcn_b1[c])); });
    __syncthreads();
    gconvIP(W5, SS, 512);
    __syncthreads();
    gemmM<16, 2>(W5, SS, ws + OFF_GCN_W2, 16, 0, 16,
        [&](int rr, int c, float v) { R[rr * RS + c] += v + P.gcn_b2[c]; });  // x_a
    __syncthreads();

    // ---------------- Mamba ----------------
    for (int i = tid; i < 17 * 256; i += NTHR) {
        int rr = i >> 8, d = i & 255;
        AC[rr * TS + d] = f2b(R[HOPA[rr] * RS + d] + P.bp_embed[BPEI[rr] * 256 + d]);
    }
    __syncthreads();
    ln17([&](int rr, int d) { return b2f(AC[rr * TS + d]); }, T1, P.ssm_ln_g, P.ssm_ln_b);
    __syncthreads();
    // xm = silu(conv(in_proj[:, :512]))
    gemmM<8, 4>(T1, TS, ws + OFF_INPROJ, 64, 0, 32,
        [&](int rr, int c, float v) { W5[rr * SS + c] = f2b(siluf(v * P.conv_w[c] + P.conv_b[c])); });
    __syncthreads();
    // x_proj (N=24 padded to 32)
    gemmM<16, 1>(W5, SS, ws + OFF_XPROJ, 2, 0, 2,
        [&](int rr, int c, float v) { if (c < 24) Dbl[rr * 24 + c] = v; });
    __syncthreads();
    // selective scan: thread owns channel d (512 indep chains)
    {
        const int d = tid;
        float wdt[16];
        #pragma unroll
        for (int r = 0; r < 16; ++r) wdt[r] = P.dt_proj_w[r * 512 + d];
        const float dtb = P.dt_proj_b[d];
        float Ar[4];
        #pragma unroll
        for (int s = 0; s < 4; ++s) Ar[s] = -__expf(P.A_log[d * 4 + s]);
        const float Dpd = P.Dp[d];
        float h0 = 0.f, h1 = 0.f, h2 = 0.f, h3 = 0.f;
        for (int t = 0; t < LSEQ; ++t) {
            const float* Dv = Dbl + t * 24;
            float a = dtb;
            #pragma unroll
            for (int r = 0; r < 16; ++r) a += Dv[r] * wdt[r];
            float dt_ = softplusf(a);
            float xm = b2f(W5[t * SS + d]);
            float p = dt_ * xm;
            h0 = __expf(dt_ * Ar[0]) * h0 + p * Dv[16];
            h1 = __expf(dt_ * Ar[1]) * h1 + p * Dv[17];
            h2 = __expf(dt_ * Ar[2]) * h2 + p * Dv[18];
            h3 = __expf(dt_ * Ar[3]) * h3 + p * Dv[19];
            float y = h0 * Dv[20] + h1 * Dv[21] + h2 * Dv[22] + h3 * Dv[23] + Dpd * xm;
            W5[t * SS + d] = f2b(y);
        }
    }
    __syncthreads();
    // z half of in_proj; gate y in place
    gemmM<8, 4>(T1, TS, ws + OFF_INPROJ, 64, 32, 32,
        [&](int rr, int c, float v) {
            float y = b2f(W5[rr * SS + c]);
            W5[rr * SS + c] = f2b(y * siluf(v));
        });
    __syncthreads();
    gemmM<16, 2>(W5, SS, ws + OFF_OUTPROJ, 16, 0, 16,
        [&](int rr, int c, float v) { AC[rr * TS + c] = f2b(v); });
    __syncthreads();
    // x_b = 2*x_a + scatter(mamba_out)
    for (int i = tid; i < 17 * 256; i += NTHR) {
        int rr = i >> 8, d = i & 255;
        R[rr * RS + d] = 2.0f * R[rr * RS + d] + b2f(AC[GRAPHA[rr] * TS + d]);
    }
    __syncthreads();

    // ---------------- Attention ----------------
    ln17([&](int rr, int d) { return R[rr * RS + d]; }, AC, P.ln1_g, P.ln1_b);
    __syncthreads();
    // QKV in two passes (tiles 0-23, 24-47). abs col cc: <256 Q -> T1; else K|V -> W5
    gemmM<8, 3>(AC, TS, ws + OFF_QKV, 48, 0, 24,
        [&](int rr, int c, float v) {
            if (c < 256) T1[rr * TS + c] = f2b(v);
            else         W5[rr * SS + (c - 256)] = f2b(v);
        });
    gemmM<8, 3>(AC, TS, ws + OFF_QKV, 48, 24, 24,
        [&](int rr, int c, float v) {
            W5[rr * SS + (c + 128)] = f2b(v);  // cc = c+384 -> W5 col cc-256
        });
    __syncthreads();
    // QK^T via MFMA: wave = head. Q rows (T1) = A-frags, K rows (W5) = B-frags.
    // SC[h][i][0..31] zero-padded beyond j=16 (gated B-frag => exact zeros).
    {
        const int h = wv, m16 = lane & 15, quad = lane >> 4;
        const u16* qb = T1 + h * 32 + quad * 8;
        const u16* kb = W5 + h * 32 + quad * 8;
        short8 qa0 = *(const short8*)(qb + m16 * TS);
        short8 ka0 = *(const short8*)(kb + m16 * SS);
        short8 qa1 = {0,0,0,0,0,0,0,0}, ka1 = {0,0,0,0,0,0,0,0};
        if (m16 == 0) {
            qa1 = *(const short8*)(qb + 16 * TS);
            ka1 = *(const short8*)(kb + 16 * SS);
        }
        f32x4 s00 = {0.f,0.f,0.f,0.f}, s01 = s00, s10 = s00, s11 = s00;
        s00 = __builtin_amdgcn_mfma_f32_16x16x32_bf16(qa0, ka0, s00, 0, 0, 0);
        s01 = __builtin_amdgcn_mfma_f32_16x16x32_bf16(qa0, ka1, s01, 0, 0, 0);
        s10 = __builtin_amdgcn_mfma_f32_16x16x32_bf16(qa1, ka0, s10, 0, 0, 0);
        s11 = __builtin_amdgcn_mfma_f32_16x16x32_bf16(qa1, ka1, s11, 0, 0, 0);
        const float sc = 0.17677669529663687f;
        u16* sh = SC + h * 17 * SCS;
        #pragma unroll
        for (int r = 0; r < 4; ++r) {
            int i = quad * 4 + r;
            sh[i * SCS + m16]      = f2b(s00[r] * sc);
            sh[i * SCS + 16 + m16] = f2b(s01[r] * sc);
        }
        if (quad == 0) {  // row 16 = tile1 row (quad*4+r)==0
            sh[16 * SCS + m16]      = f2b(s10[0] * sc);
            sh[16 * SCS + 16 + m16] = f2b(s11[0] * sc);
        }
    }
    __syncthreads();
    if (tid < 136) {  // 8 heads x 17 rows
        u16* row = SC + tid * SCS;
        float e[17], mx = -3.0e38f, sum = 0.f;
        #pragma unroll
        for (int j = 0; j < 17; ++j) mx = fmaxf(mx, b2f(row[j]));
        #pragma unroll
        for (int j = 0; j < 17; ++j) { e[j] = __expf(b2f(row[j]) - mx); sum += e[j]; }
        float inv = 1.0f / sum;
        #pragma unroll
        for (int j = 0; j < 17; ++j) row[j] = f2b(e[j] * inv);
    }
    __syncthreads();
    // AV via MFMA: A = att rows (SC, k-padded zeros), B = V[token k][chan n]
    // from W5 cols 256..511, masked k<17 loads. o -> AC.
    {
        const int h = wv, m16 = lane & 15, quad = lane >> 4;
        const u16* sh = SC + h * 17 * SCS + quad * 8;
        short8 pa0 = *(const short8*)(sh + m16 * SCS);
        short8 pa1 = {0,0,0,0,0,0,0,0};
        if (m16 == 0) pa1 = *(const short8*)(sh + 16 * SCS);
        f32x4 o0[2], o1[2];
        #pragma unroll
        for (int nt = 0; nt < 2; ++nt) { o0[nt] = (f32x4){0.f,0.f,0.f,0.f}; o1[nt] = o0[nt]; }
        #pragma unroll
        for (int nt = 0; nt < 2; ++nt) {
            const u16* vbase = W5 + 256 + h * 32 + nt * 16 + m16;
            short8 vb;
            #pragma unroll
            for (int j = 0; j < 8; ++j) {
                int k = quad * 8 + j;
                vb[j] = (k < 17) ? (short)vbase[k * SS] : (short)0;
            }
            o0[nt] = __builtin_amdgcn_mfma_f32_16x16x32_bf16(pa0, vb, o0[nt], 0, 0, 0);
            o1[nt] = __builtin_amdgcn_mfma_f32_16x16x32_bf16(pa1, vb, o1[nt], 0, 0, 0);
        }
        #pragma unroll
        for (int nt = 0; nt < 2; ++nt) {
            #pragma unroll
            for (int r = 0; r < 4; ++r) {
                int i = quad * 4 + r;
                AC[i * TS + h * 32 + nt * 16 + m16] = f2b(o0[nt][r]);
            }
            if (quad == 0)
                AC[16 * TS + h * 32 + nt * 16 + m16] = f2b(o1[nt][0]);
        }
    }
    __syncthreads();
    // o' = attn_proj(o) + bias
    gemmM<8, 2>(AC, TS, ws + OFF_ATTNPROJ, 16, 0, 16,
        [&](int rr, int c, float v) { T1[rr * TS + c] = f2b(v + P.attn_proj_b[c]); });
    __syncthreads();

    // ---------------- MLP + final ----------------
    ln17([&](int rr, int d) { return R[rr * RS + d] + b2f(T1[rr * TS + d]); },
         AC, P.ln2_g, P.ln2_b);
    __syncthreads();
    {
        f32x4 accO[2][2];
        #pragma unroll
        for (int mt = 0; mt < 2; ++mt)
            #pragma unroll
            for (int i = 0; i < 2; ++i) accO[mt][i] = (f32x4){0.f,0.f,0.f,0.f};
        #pragma unroll
        for (int half = 0; half < 2; ++half) {
            gemmM<8, 4>(AC, TS, ws + OFF_MLP_W1, 64, half * 32, 32,
                [&](int rr, int c, float v) {
                    W5[rr * SS + c] = f2b(gelu_t(v + P.mlp_b1[half * 512 + c]));
                });
            __syncthreads();
            mfmaAcc<16, 2>(accO, W5, SS, ws + OFF_MLP_W2, 16, 0, 16, half * 16);
            __syncthreads();  // W5 reused next half
        }
        float* outg = P.out + (size_t)blockIdx.x * (LSEQ * 256);
        mfmaStore<2>(accO, 16, [&](int rr, int c, float v) {
            float r = v + P.mlp_b2[c] + 2.0f * R[rr * RS + c] + b2f(T1[rr * TS + c]);
            __builtin_nontemporal_store(r, outg + rr * 256 + c);
        });
    }
}

extern "C" void kernel_launch(void* const* d_in, const int* in_sizes, int n_in,
                              void* d_out, int out_size, void* d_ws, size_t ws_size,
                              hipStream_t stream) {
    (void)in_sizes; (void)n_in; (void)ws_size; (void)out_size;
    Params P;
    P.x           = (const float*)d_in[0];
    P.gcn_ln_g    = (const float*)d_in[1];
    P.gcn_ln_b    = (const float*)d_in[2];
    P.gcn_w1      = (const float*)d_in[3];
    P.gcn_b1      = (const float*)d_in[4];
    P.gcn_w2      = (const float*)d_in[5];
    P.gcn_b2      = (const float*)d_in[6];
    P.bp_embed    = (const float*)d_in[7];
    P.ssm_ln_g    = (const float*)d_in[8];
    P.ssm_ln_b    = (const float*)d_in[9];
    P.in_proj_w   = (const float*)d_in[10];
    P.conv_w      = (const float*)d_in[11];
    P.conv_b      = (const float*)d_in[12];
    P.x_proj_w    = (const float*)d_in[13];
    P.dt_proj_w   = (const float*)d_in[14];
    P.dt_proj_b   = (const float*)d_in[15];
    P.A_log       = (const float*)d_in[16];
    P.Dp          = (const float*)d_in[17];
    P.out_proj_w  = (const float*)d_in[18];
    P.ln1_g       = (const float*)d_in[19];
    P.ln1_b       = (const float*)d_in[20];
    P.qkv_w       = (const float*)d_in[21];
    P.attn_proj_w = (const float*)d_in[22];
    P.attn_proj_b = (const float*)d_in[23];
    P.ln2_g       = (const float*)d_in[24];
    P.ln2_b       = (const float*)d_in[25];
    P.mlp_w1      = (const float*)d_in[26];
    P.mlp_b1      = (const float*)d_in[27];
    P.mlp_w2      = (const float*)d_in[28];
    P.mlp_b2      = (const float*)d_in[29];
    P.wws         = (const u16*)d_ws;
    P.out         = (float*)d_out;
    static int smem_set = 0;
    if (!smem_set) {
        hipFuncSetAttribute(reinterpret_cast<const void*>(fused_block),
                            hipFuncAttributeMaxDynamicSharedMemorySize, SMEM_BYTES);
        smem_set = 1;
    }
    hipLaunchKernelGGL(prepack, dim3(712), dim3(256), 0, stream, P);
    hipLaunchKernelGGL(fused_block, dim3(4096), dim3(NTHR), SMEM_BYTES, stream, P);
}

// Round 6
// 1194.746 us; speedup vs baseline: 1.7296x; 1.1243x over previous
//
#include <hip/hip_runtime.h>
#include <hip/hip_bf16.h>
#include <math.h>

// R11: R10 + 768 threads (12 waves = 3 waves/SIMD, was 2). Co-residency never
// fires (occupancy pinned at 1 block/CU across 60-117KB LDS), so raise waves
// inside the one resident block. 12-wave budget = 512/3 = 170 VGPR; peak usage
// stays ~76 (widest GEMM NT4 4->3; QKV single-pass NT4=4 = same 32 acc regs).
// Scan gated tid<512, attention MFMA gated wv<8. QKV one pass (saves a full
// A-frag re-read pass). LDS unchanged 63.9 KB.

#define LSEQ 17
#define RS 256   // R row stride (f32)
#define TS 264   // AC/T1 row stride (u16)
#define SS 520   // W5 row stride (u16)
#define SCS 40   // SC row stride (u16)
#define NTHR 768
#define NWAVE 12

typedef unsigned short u16;
typedef __attribute__((ext_vector_type(8))) short short8;
typedef __attribute__((ext_vector_type(4))) float f32x4;

__device__ __forceinline__ float b2f(u16 u) {
    union { unsigned int i; float f; } x; x.i = ((unsigned int)u) << 16; return x.f;
}
__device__ __forceinline__ u16 f2b(float f) {
    union { float f; unsigned int i; } x; x.f = f;
    unsigned int r = x.i + 0x7FFFu + ((x.i >> 16) & 1u);
    return (u16)(r >> 16);
}
__device__ __forceinline__ float gelu_t(float x) {
    float u = 1.5957691216057308f * (x + 0.044715f * x * x * x);
    return x / (1.0f + __expf(-u));
}
__device__ __forceinline__ float siluf(float x) { return x / (1.0f + __expf(-x)); }
__device__ __forceinline__ float softplusf(float x) {
    return (x > 20.0f) ? x : __logf(1.0f + __expf(x));
}

__device__ const int HOPA[17]   = {0,1,4,7,2,5,8,3,6,9,11,14,10,12,15,13,16};
__device__ const int GRAPHA[17] = {0,1,4,7,2,5,8,3,6,9,12,10,13,15,11,14,16};
__device__ const int BPEI[17]   = {0,1,2,0,1,2,0,1,2,0,3,4,0,3,4,3,4};

// ws fragment offsets (elements, bf16)
#define OFF_GCN_W1   0
#define OFF_GCN_W2   131072
#define OFF_INPROJ   262144
#define OFF_OUTPROJ  524288
#define OFF_QKV      655360
#define OFF_ATTNPROJ 851968
#define OFF_MLP_W1   917504
#define OFF_MLP_W2   1179648
#define OFF_XPROJ    1441792

// dynamic LDS carve (bytes) — 1 element: 17 rows
#define SM_R    0        // [17][256] f32 = 17408
#define SM_AC   17408    // [17][264] u16 = 8976
#define SM_T1   26384    // [17][264] u16 = 8976
#define SM_W5   35360    // [17][520] u16 = 17680
#define SM_U    53040    // union: Dbl [17][24] f32 (1632) | SC [8][17][40] u16 (10880)
#define SMEM_BYTES 63920

struct Params {
    const float *x, *gcn_ln_g, *gcn_ln_b, *gcn_w1, *gcn_b1, *gcn_w2, *gcn_b2,
                *bp_embed, *ssm_ln_g, *ssm_ln_b, *in_proj_w, *conv_w, *conv_b,
                *x_proj_w, *dt_proj_w, *dt_proj_b, *A_log, *Dp, *out_proj_w,
                *ln1_g, *ln1_b, *qkv_w, *attn_proj_w, *attn_proj_b,
                *ln2_g, *ln2_b, *mlp_w1, *mlp_b1, *mlp_w2, *mlp_b2;
    const u16* wws;
    float* out;
};

// ---------------- weight prepack: fp32 [K][N] -> bf16 B-fragments ----------------
__global__ __launch_bounds__(256) void prepack(Params P) {
    const int gid = blockIdx.x * 256 + threadIdx.x;
    const int cnt[9]  = {16384,16384,32768,16384,24576,8192,32768,32768,2048};
    const int Ns [9]  = {512,256,1024,256,768,256,1024,256,24};
    const int NPs[9]  = {512,256,1024,256,768,256,1024,256,32};
    const int offs[9] = {OFF_GCN_W1,OFF_GCN_W2,OFF_INPROJ,OFF_OUTPROJ,OFF_QKV,
                         OFF_ATTNPROJ,OFF_MLP_W1,OFF_MLP_W2,OFF_XPROJ};
    int e = 0, base = 0;
    while (e < 9 && gid >= base + cnt[e]) { base += cnt[e]; ++e; }
    if (e >= 9) return;
    const float* W;
    switch (e) {
        case 0: W = P.gcn_w1; break;      case 1: W = P.gcn_w2; break;
        case 2: W = P.in_proj_w; break;   case 3: W = P.out_proj_w; break;
        case 4: W = P.qkv_w; break;       case 5: W = P.attn_proj_w; break;
        case 6: W = P.mlp_w1; break;      case 7: W = P.mlp_w2; break;
        default: W = P.x_proj_w; break;
    }
    const int local = gid - base;
    const int lane = local & 63, frag = local >> 6;
    const int NT = NPs[e] >> 4;
    const int nt = frag % NT, kc = frag / NT;
    const int n = nt * 16 + (lane & 15);
    const int kbase = kc * 32 + (lane >> 4) * 8;
    u16 v[8];
    #pragma unroll
    for (int j = 0; j < 8; ++j)
        v[j] = (n < Ns[e]) ? f2b(W[(size_t)(kbase + j) * Ns[e] + n]) : (u16)0;
    u16* dst = (u16*)P.wws + offs[e] + ((size_t)frag * 64 + lane) * 8;
    *(short8*)dst = *(short8*)v;
}

// ---------------- MFMA helpers: 2 M-tiles over 17 rows, 12 waves ----------------
template <int KT, int NT4>
__device__ __forceinline__ void mfmaAcc(f32x4 acc[2][NT4],
        const u16* __restrict__ act, int ldin,
        const u16* __restrict__ wbase, int NT, int nt0, int ntcnt, int kc0) {
    const int lane = threadIdx.x & 63, wv = threadIdx.x >> 6;
    const int m = lane & 15, quad = lane >> 4;
    const bool v1 = (m < 1);
    for (int kc = 0; kc < KT; ++kc) {
        const int ko = kc * 32 + quad * 8;
        short8 a0 = *(const short8*)(act + m * ldin + ko);
        short8 a1 = {0,0,0,0,0,0,0,0};
        if (v1) a1 = *(const short8*)(act + 16 * ldin + ko);
        #pragma unroll
        for (int i = 0; i < NT4; ++i) {
            const int ntl = wv + NWAVE * i;
            if (ntl < ntcnt) {
                const short8 b = *(const short8*)(wbase +
                    ((size_t)((kc0 + kc) * NT + nt0 + ntl) * 64 + lane) * 8);
                acc[0][i] = __builtin_amdgcn_mfma_f32_16x16x32_bf16(a0, b, acc[0][i], 0, 0, 0);
                acc[1][i] = __builtin_amdgcn_mfma_f32_16x16x32_bf16(a1, b, acc[1][i], 0, 0, 0);
            }
        }
    }
}

// epi(rr, c_rel, val): rr in [0,17) row, c_rel relative to nt0*16.
template <int NT4, class Epi>
__device__ __forceinline__ void mfmaStore(f32x4 acc[2][NT4], int ntcnt, Epi epi) {
    const int lane = threadIdx.x & 63, wv = threadIdx.x >> 6;
    const int col0 = lane & 15, quad = lane >> 4;
    #pragma unroll
    for (int i = 0; i < NT4; ++i) {
        const int ntl = wv + NWAVE * i;
        if (ntl < ntcnt) {
            const int cb = ntl * 16 + col0;
            #pragma unroll
            for (int r = 0; r < 4; ++r) epi(quad * 4 + r, cb, acc[0][i][r]);
            if (quad == 0) epi(16, cb, acc[1][i][0]);
        }
    }
}

template <int KT, int NT4, class Epi>
__device__ __forceinline__ void gemmM(const u16* act, int ldin,
        const u16* wbase, int NT, int nt0, int ntcnt, Epi epi) {
    f32x4 acc[2][NT4];
    #pragma unroll
    for (int mt = 0; mt < 2; ++mt)
        #pragma unroll
        for (int i = 0; i < NT4; ++i) acc[mt][i] = (f32x4){0.f,0.f,0.f,0.f};
    mfmaAcc<KT, NT4>(acc, act, ldin, wbase, NT, nt0, ntcnt, 0);
    mfmaStore<NT4>(acc, ntcnt, epi);
}

// ---------------- main fused kernel: 1 element per block ----------------
__global__ __launch_bounds__(NTHR, 3) void fused_block(Params P) {
    extern __shared__ __align__(16) char smem[];
    float* R   = (float*)(smem + SM_R);    // [17][256] f32
    u16*   AC  = (u16*)  (smem + SM_AC);   // [17][264]
    u16*   T1  = (u16*)  (smem + SM_T1);   // [17][264]
    u16*   W5  = (u16*)  (smem + SM_W5);   // [17][520]
    float* Dbl = (float*)(smem + SM_U);    // [17][24] (mamba only)
    u16*   SC  = (u16*)  (smem + SM_U);    // [8][17][40] (attention only)

    const int tid = threadIdx.x;
    const int lane = tid & 63, wv = tid >> 6;
    const float* __restrict__ xg = P.x + (size_t)blockIdx.x * (LSEQ * 256);
    const u16* __restrict__ ws = P.wws;

    // x -> R (17 rows), non-temporal float4
    for (int i4 = tid; i4 < 17 * 64; i4 += NTHR) {
        int rr = i4 >> 6, d4 = (i4 & 63) * 4;
        f32x4 v = __builtin_nontemporal_load((const f32x4*)(xg + rr * 256 + d4));
        *(f32x4*)(R + rr * RS + d4) = v;
    }
    __syncthreads();

    auto ln17 = [&](auto ld, u16* dst, const float* g, const float* bb) {
        for (int rr = wv; rr < 17; rr += NWAVE) {
            float v[4], s = 0.f, s2 = 0.f;
            #pragma unroll
            for (int j = 0; j < 4; ++j) {
                v[j] = ld(rr, lane + 64 * j);
                s += v[j]; s2 += v[j] * v[j];
            }
            #pragma unroll
            for (int m = 1; m < 64; m <<= 1) {
                s  += __shfl_xor(s, m, 64);
                s2 += __shfl_xor(s2, m, 64);
            }
            float mean = s * (1.0f / 256.0f);
            float var  = s2 * (1.0f / 256.0f) - mean * mean;
            float rstd = rsqrtf(var + 1e-5f);
            #pragma unroll
            for (int j = 0; j < 4; ++j) {
                int d = lane + 64 * j;
                dst[rr * TS + d] = f2b((v[j] - mean) * rstd * g[d] + bb[d]);
            }
        }
    };
    // sparse graph conv (49 nonzeros, compile-time weights), in place;
    // thread owns a full column (race-free)
    auto gconvIP = [&](u16* buf, int stride, int width) {
        if (tid < width) {
            const int d = tid;
            float c[17];
            #pragma unroll
            for (int j = 0; j < 17; ++j) c[j] = b2f(buf[j * stride + d]);
            float o[17];
            o[0]  = 0.25f*c[0] + 0.28867513f*(c[1]+c[4]+c[7]);
            o[1]  = 0.28867513f*c[0] + 0.33333334f*(c[1]+c[2]);
            o[2]  = 0.33333334f*(c[1]+c[2]) + 0.40824829f*c[3];
            o[3]  = 0.40824829f*c[2] + 0.5f*c[3];
            o[4]  = 0.28867513f*c[0] + 0.33333334f*(c[4]+c[5]);
            o[5]  = 0.33333334f*(c[4]+c[5]) + 0.40824829f*c[6];
            o[6]  = 0.40824829f*c[5] + 0.5f*c[6];
            o[7]  = 0.28867513f*c[0] + 0.33333334f*c[7] + 0.25819889f*c[8];
            o[8]  = 0.25819889f*(c[7]+c[9]+c[11]+c[14]) + 0.2f*c[8];
            o[9]  = 0.25819889f*c[8] + 0.33333334f*c[9] + 0.40824829f*c[10];
            o[10] = 0.40824829f*c[9] + 0.5f*c[10];
            o[11] = 0.25819889f*c[8] + 0.33333334f*(c[11]+c[12]);
            o[12] = 0.33333334f*(c[11]+c[12]) + 0.40824829f*c[13];
            o[13] = 0.40824829f*c[12] + 0.5f*c[13];
            o[14] = 0.25819889f*c[8] + 0.33333334f*(c[14]+c[15]);
            o[15] = 0.33333334f*(c[14]+c[15]) + 0.40824829f*c[16];
            o[16] = 0.40824829f*c[15] + 0.5f*c[16];
            #pragma unroll
            for (int i = 0; i < 17; ++i) buf[i * stride + d] = f2b(o[i]);
        }
    };

    // ---------------- GCN ----------------
    ln17([&](int rr, int d) { return R[rr * RS + d]; }, AC, P.gcn_ln_g, P.gcn_ln_b);
    __syncthreads();
    gconvIP(AC, TS, 256);
    __syncthreads();
    gemmM<8, 3>(AC, TS, ws + OFF_GCN_W1, 32, 0, 32,
        [&](int rr, int c, float v) { W5[rr * SS + c] = f2b(gelu_t(v + P.gcn_b1[c])); });
    __syncthreads();
    gconvIP(W5, SS, 512);
    __syncthreads();
    gemmM<16, 2>(W5, SS, ws + OFF_GCN_W2, 16, 0, 16,
        [&](int rr, int c, float v) { R[rr * RS + c] += v + P.gcn_b2[c]; });  // x_a
    __syncthreads();

    // ---------------- Mamba ----------------
    for (int i = tid; i < 17 * 256; i += NTHR) {
        int rr = i >> 8, d = i & 255;
        AC[rr * TS + d] = f2b(R[HOPA[rr] * RS + d] + P.bp_embed[BPEI[rr] * 256 + d]);
    }
    __syncthreads();
    ln17([&](int rr, int d) { return b2f(AC[rr * TS + d]); }, T1, P.ssm_ln_g, P.ssm_ln_b);
    __syncthreads();
    // xm = silu(conv(in_proj[:, :512]))
    gemmM<8, 3>(T1, TS, ws + OFF_INPROJ, 64, 0, 32,
        [&](int rr, int c, float v) { W5[rr * SS + c] = f2b(siluf(v * P.conv_w[c] + P.conv_b[c])); });
    __syncthreads();
    // x_proj (N=24 padded to 32)
    gemmM<16, 1>(W5, SS, ws + OFF_XPROJ, 2, 0, 2,
        [&](int rr, int c, float v) { if (c < 24) Dbl[rr * 24 + c] = v; });
    __syncthreads();
    // selective scan: thread owns channel d (512 indep chains; waves 8-11 idle)
    if (tid < 512) {
        const int d = tid;
        float wdt[16];
        #pragma unroll
        for (int r = 0; r < 16; ++r) wdt[r] = P.dt_proj_w[r * 512 + d];
        const float dtb = P.dt_proj_b[d];
        float Ar[4];
        #pragma unroll
        for (int s = 0; s < 4; ++s) Ar[s] = -__expf(P.A_log[d * 4 + s]);
        const float Dpd = P.Dp[d];
        float h0 = 0.f, h1 = 0.f, h2 = 0.f, h3 = 0.f;
        for (int t = 0; t < LSEQ; ++t) {
            const float* Dv = Dbl + t * 24;
            float a = dtb;
            #pragma unroll
            for (int r = 0; r < 16; ++r) a += Dv[r] * wdt[r];
            float dt_ = softplusf(a);
            float xm = b2f(W5[t * SS + d]);
            float p = dt_ * xm;
            h0 = __expf(dt_ * Ar[0]) * h0 + p * Dv[16];
            h1 = __expf(dt_ * Ar[1]) * h1 + p * Dv[17];
            h2 = __expf(dt_ * Ar[2]) * h2 + p * Dv[18];
            h3 = __expf(dt_ * Ar[3]) * h3 + p * Dv[19];
            float y = h0 * Dv[20] + h1 * Dv[21] + h2 * Dv[22] + h3 * Dv[23] + Dpd * xm;
            W5[t * SS + d] = f2b(y);
        }
    }
    __syncthreads();
    // z half of in_proj; gate y in place
    gemmM<8, 3>(T1, TS, ws + OFF_INPROJ, 64, 32, 32,
        [&](int rr, int c, float v) {
            float y = b2f(W5[rr * SS + c]);
            W5[rr * SS + c] = f2b(y * siluf(v));
        });
    __syncthreads();
    gemmM<16, 2>(W5, SS, ws + OFF_OUTPROJ, 16, 0, 16,
        [&](int rr, int c, float v) { AC[rr * TS + c] = f2b(v); });
    __syncthreads();
    // x_b = 2*x_a + scatter(mamba_out)
    for (int i = tid; i < 17 * 256; i += NTHR) {
        int rr = i >> 8, d = i & 255;
        R[rr * RS + d] = 2.0f * R[rr * RS + d] + b2f(AC[GRAPHA[rr] * TS + d]);
    }
    __syncthreads();

    // ---------------- Attention ----------------
    ln17([&](int rr, int d) { return R[rr * RS + d]; }, AC, P.ln1_g, P.ln1_b);
    __syncthreads();
    // QKV single pass: 48 N-tiles over 12 waves (NT4=4).
    // abs col c: <256 Q -> T1; else K (256-511) | V (512-767) -> W5 col c-256
    gemmM<8, 4>(AC, TS, ws + OFF_QKV, 48, 0, 48,
        [&](int rr, int c, float v) {
            if (c < 256) T1[rr * TS + c] = f2b(v);
            else         W5[rr * SS + (c - 256)] = f2b(v);
        });
    __syncthreads();
    // QK^T via MFMA: wave = head (waves 8-11 idle). Q rows (T1) = A-frags,
    // K rows (W5) = B-frags. SC zero-padded beyond j=16 (gated B-frag).
    if (wv < 8) {
        const int h = wv, m16 = lane & 15, quad = lane >> 4;
        const u16* qb = T1 + h * 32 + quad * 8;
        const u16* kb = W5 + h * 32 + quad * 8;
        short8 qa0 = *(const short8*)(qb + m16 * TS);
        short8 ka0 = *(const short8*)(kb + m16 * SS);
        short8 qa1 = {0,0,0,0,0,0,0,0}, ka1 = {0,0,0,0,0,0,0,0};
        if (m16 == 0) {
            qa1 = *(const short8*)(qb + 16 * TS);
            ka1 = *(const short8*)(kb + 16 * SS);
        }
        f32x4 s00 = {0.f,0.f,0.f,0.f}, s01 = s00, s10 = s00, s11 = s00;
        s00 = __builtin_amdgcn_mfma_f32_16x16x32_bf16(qa0, ka0, s00, 0, 0, 0);
        s01 = __builtin_amdgcn_mfma_f32_16x16x32_bf16(qa0, ka1, s01, 0, 0, 0);
        s10 = __builtin_amdgcn_mfma_f32_16x16x32_bf16(qa1, ka0, s10, 0, 0, 0);
        s11 = __builtin_amdgcn_mfma_f32_16x16x32_bf16(qa1, ka1, s11, 0, 0, 0);
        const float sc = 0.17677669529663687f;
        u16* sh = SC + h * 17 * SCS;
        #pragma unroll
        for (int r = 0; r < 4; ++r) {
            int i = quad * 4 + r;
            sh[i * SCS + m16]      = f2b(s00[r] * sc);
            sh[i * SCS + 16 + m16] = f2b(s01[r] * sc);
        }
        if (quad == 0) {  // row 16 = tile1 row (quad*4+r)==0
            sh[16 * SCS + m16]      = f2b(s10[0] * sc);
            sh[16 * SCS + 16 + m16] = f2b(s11[0] * sc);
        }
    }
    __syncthreads();
    if (tid < 136) {  // 8 heads x 17 rows
        u16* row = SC + tid * SCS;
        float e[17], mx = -3.0e38f, sum = 0.f;
        #pragma unroll
        for (int j = 0; j < 17; ++j) mx = fmaxf(mx, b2f(row[j]));
        #pragma unroll
        for (int j = 0; j < 17; ++j) { e[j] = __expf(b2f(row[j]) - mx); sum += e[j]; }
        float inv = 1.0f / sum;
        #pragma unroll
        for (int j = 0; j < 17; ++j) row[j] = f2b(e[j] * inv);
    }
    __syncthreads();
    // AV via MFMA: A = att rows (SC, k-padded zeros), B = V[token k][chan n]
    // from W5 cols 256..511, masked k<17 loads. o -> AC.
    if (wv < 8) {
        const int h = wv, m16 = lane & 15, quad = lane >> 4;
        const u16* sh = SC + h * 17 * SCS + quad * 8;
        short8 pa0 = *(const short8*)(sh + m16 * SCS);
        short8 pa1 = {0,0,0,0,0,0,0,0};
        if (m16 == 0) pa1 = *(const short8*)(sh + 16 * SCS);
        f32x4 o0[2], o1[2];
        #pragma unroll
        for (int nt = 0; nt < 2; ++nt) { o0[nt] = (f32x4){0.f,0.f,0.f,0.f}; o1[nt] = o0[nt]; }
        #pragma unroll
        for (int nt = 0; nt < 2; ++nt) {
            const u16* vbase = W5 + 256 + h * 32 + nt * 16 + m16;
            short8 vb;
            #pragma unroll
            for (int j = 0; j < 8; ++j) {
                int k = quad * 8 + j;
                vb[j] = (k < 17) ? (short)vbase[k * SS] : (short)0;
            }
            o0[nt] = __builtin_amdgcn_mfma_f32_16x16x32_bf16(pa0, vb, o0[nt], 0, 0, 0);
            o1[nt] = __builtin_amdgcn_mfma_f32_16x16x32_bf16(pa1, vb, o1[nt], 0, 0, 0);
        }
        #pragma unroll
        for (int nt = 0; nt < 2; ++nt) {
            #pragma unroll
            for (int r = 0; r < 4; ++r) {
                int i = quad * 4 + r;
                AC[i * TS + h * 32 + nt * 16 + m16] = f2b(o0[nt][r]);
            }
            if (quad == 0)
                AC[16 * TS + h * 32 + nt * 16 + m16] = f2b(o1[nt][0]);
        }
    }
    __syncthreads();
    // o' = attn_proj(o) + bias
    gemmM<8, 2>(AC, TS, ws + OFF_ATTNPROJ, 16, 0, 16,
        [&](int rr, int c, float v) { T1[rr * TS + c] = f2b(v + P.attn_proj_b[c]); });
    __syncthreads();

    // ---------------- MLP + final ----------------
    ln17([&](int rr, int d) { return R[rr * RS + d] + b2f(T1[rr * TS + d]); },
         AC, P.ln2_g, P.ln2_b);
    __syncthreads();
    {
        f32x4 accO[2][2];
        #pragma unroll
        for (int mt = 0; mt < 2; ++mt)
            #pragma unroll
            for (int i = 0; i < 2; ++i) accO[mt][i] = (f32x4){0.f,0.f,0.f,0.f};
        #pragma unroll
        for (int half = 0; half < 2; ++half) {
            gemmM<8, 3>(AC, TS, ws + OFF_MLP_W1, 64, half * 32, 32,
                [&](int rr, int c, float v) {
                    W5[rr * SS + c] = f2b(gelu_t(v + P.mlp_b1[half * 512 + c]));
                });
            __syncthreads();
            mfmaAcc<16, 2>(accO, W5, SS, ws + OFF_MLP_W2, 16, 0, 16, half * 16);
            __syncthreads();  // W5 reused next half
        }
        float* outg = P.out + (size_t)blockIdx.x * (LSEQ * 256);
        mfmaStore<2>(accO, 16, [&](int rr, int c, float v) {
            float r = v + P.mlp_b2[c] + 2.0f * R[rr * RS + c] + b2f(T1[rr * TS + c]);
            __builtin_nontemporal_store(r, outg + rr * 256 + c);
        });
    }
}

extern "C" void kernel_launch(void* const* d_in, const int* in_sizes, int n_in,
                              void* d_out, int out_size, void* d_ws, size_t ws_size,
                              hipStream_t stream) {
    (void)in_sizes; (void)n_in; (void)ws_size; (void)out_size;
    Params P;
    P.x           = (const float*)d_in[0];
    P.gcn_ln_g    = (const float*)d_in[1];
    P.gcn_ln_b    = (const float*)d_in[2];
    P.gcn_w1      = (const float*)d_in[3];
    P.gcn_b1      = (const float*)d_in[4];
    P.gcn_w2      = (const float*)d_in[5];
    P.gcn_b2      = (const float*)d_in[6];
    P.bp_embed    = (const float*)d_in[7];
    P.ssm_ln_g    = (const float*)d_in[8];
    P.ssm_ln_b    = (const float*)d_in[9];
    P.in_proj_w   = (const float*)d_in[10];
    P.conv_w      = (const float*)d_in[11];
    P.conv_b      = (const float*)d_in[12];
    P.x_proj_w    = (const float*)d_in[13];
    P.dt_proj_w   = (const float*)d_in[14];
    P.dt_proj_b   = (const float*)d_in[15];
    P.A_log       = (const float*)d_in[16];
    P.Dp          = (const float*)d_in[17];
    P.out_proj_w  = (const float*)d_in[18];
    P.ln1_g       = (const float*)d_in[19];
    P.ln1_b       = (const float*)d_in[20];
    P.qkv_w       = (const float*)d_in[21];
    P.attn_proj_w = (const float*)d_in[22];
    P.attn_proj_b = (const float*)d_in[23];
    P.ln2_g       = (const float*)d_in[24];
    P.ln2_b       = (const float*)d_in[25];
    P.mlp_w1      = (const float*)d_in[26];
    P.mlp_b1      = (const float*)d_in[27];
    P.mlp_w2      = (const float*)d_in[28];
    P.mlp_b2      = (const float*)d_in[29];
    P.wws         = (const u16*)d_ws;
    P.out         = (float*)d_out;
    static int smem_set = 0;
    if (!smem_set) {
        hipFuncSetAttribute(reinterpret_cast<const void*>(fused_block),
                            hipFuncAttributeMaxDynamicSharedMemorySize, SMEM_BYTES);
        smem_set = 1;
    }
    hipLaunchKernelGGL(prepack, dim3(712), dim3(256), 0, stream, P);
    hipLaunchKernelGGL(fused_block, dim3(4096), dim3(NTHR), SMEM_BYTES, stream, P);
}

// Round 7
// 989.703 us; speedup vs baseline: 2.0879x; 1.2072x over previous
//
#include <hip/hip_runtime.h>
#include <hip/hip_bf16.h>
#include <math.h>

// R12: R11 + 1024 threads (16 waves = 4 waves/SIMD, was 3). R11 proved the
// 2-Mtile footprint runs spill-free at 64 VGPR, so the R6 spill trap was the
// old 3-Mtile register load, not thread count. Per-wave tiles shrink further
// at NWAVE=16 (QKV NT4 3, GEMMs 2, MLP_W2 1). Attention QK^T/AV split across
// all 16 waves: wave=(half,head); half 0 = rows 0-15 tile, half 1 = row 16.
// Scan stays tid<512. Tripwire: spills would show as WRITE_SIZE >> 75 MB.

#define LSEQ 17
#define RS 256   // R row stride (f32)
#define TS 264   // AC/T1 row stride (u16)
#define SS 520   // W5 row stride (u16)
#define SCS 40   // SC row stride (u16)
#define NTHR 1024
#define NWAVE 16

typedef unsigned short u16;
typedef __attribute__((ext_vector_type(8))) short short8;
typedef __attribute__((ext_vector_type(4))) float f32x4;

__device__ __forceinline__ float b2f(u16 u) {
    union { unsigned int i; float f; } x; x.i = ((unsigned int)u) << 16; return x.f;
}
__device__ __forceinline__ u16 f2b(float f) {
    union { float f; unsigned int i; } x; x.f = f;
    unsigned int r = x.i + 0x7FFFu + ((x.i >> 16) & 1u);
    return (u16)(r >> 16);
}
__device__ __forceinline__ float gelu_t(float x) {
    float u = 1.5957691216057308f * (x + 0.044715f * x * x * x);
    return x / (1.0f + __expf(-u));
}
__device__ __forceinline__ float siluf(float x) { return x / (1.0f + __expf(-x)); }
__device__ __forceinline__ float softplusf(float x) {
    return (x > 20.0f) ? x : __logf(1.0f + __expf(x));
}

__device__ const int HOPA[17]   = {0,1,4,7,2,5,8,3,6,9,11,14,10,12,15,13,16};
__device__ const int GRAPHA[17] = {0,1,4,7,2,5,8,3,6,9,12,10,13,15,11,14,16};
__device__ const int BPEI[17]   = {0,1,2,0,1,2,0,1,2,0,3,4,0,3,4,3,4};

// ws fragment offsets (elements, bf16)
#define OFF_GCN_W1   0
#define OFF_GCN_W2   131072
#define OFF_INPROJ   262144
#define OFF_OUTPROJ  524288
#define OFF_QKV      655360
#define OFF_ATTNPROJ 851968
#define OFF_MLP_W1   917504
#define OFF_MLP_W2   1179648
#define OFF_XPROJ    1441792

// dynamic LDS carve (bytes) — 1 element: 17 rows
#define SM_R    0        // [17][256] f32 = 17408
#define SM_AC   17408    // [17][264] u16 = 8976
#define SM_T1   26384    // [17][264] u16 = 8976
#define SM_W5   35360    // [17][520] u16 = 17680
#define SM_U    53040    // union: Dbl [17][24] f32 (1632) | SC [8][17][40] u16 (10880)
#define SMEM_BYTES 63920

struct Params {
    const float *x, *gcn_ln_g, *gcn_ln_b, *gcn_w1, *gcn_b1, *gcn_w2, *gcn_b2,
                *bp_embed, *ssm_ln_g, *ssm_ln_b, *in_proj_w, *conv_w, *conv_b,
                *x_proj_w, *dt_proj_w, *dt_proj_b, *A_log, *Dp, *out_proj_w,
                *ln1_g, *ln1_b, *qkv_w, *attn_proj_w, *attn_proj_b,
                *ln2_g, *ln2_b, *mlp_w1, *mlp_b1, *mlp_w2, *mlp_b2;
    const u16* wws;
    float* out;
};

// ---------------- weight prepack: fp32 [K][N] -> bf16 B-fragments ----------------
__global__ __launch_bounds__(256) void prepack(Params P) {
    const int gid = blockIdx.x * 256 + threadIdx.x;
    const int cnt[9]  = {16384,16384,32768,16384,24576,8192,32768,32768,2048};
    const int Ns [9]  = {512,256,1024,256,768,256,1024,256,24};
    const int NPs[9]  = {512,256,1024,256,768,256,1024,256,32};
    const int offs[9] = {OFF_GCN_W1,OFF_GCN_W2,OFF_INPROJ,OFF_OUTPROJ,OFF_QKV,
                         OFF_ATTNPROJ,OFF_MLP_W1,OFF_MLP_W2,OFF_XPROJ};
    int e = 0, base = 0;
    while (e < 9 && gid >= base + cnt[e]) { base += cnt[e]; ++e; }
    if (e >= 9) return;
    const float* W;
    switch (e) {
        case 0: W = P.gcn_w1; break;      case 1: W = P.gcn_w2; break;
        case 2: W = P.in_proj_w; break;   case 3: W = P.out_proj_w; break;
        case 4: W = P.qkv_w; break;       case 5: W = P.attn_proj_w; break;
        case 6: W = P.mlp_w1; break;      case 7: W = P.mlp_w2; break;
        default: W = P.x_proj_w; break;
    }
    const int local = gid - base;
    const int lane = local & 63, frag = local >> 6;
    const int NT = NPs[e] >> 4;
    const int nt = frag % NT, kc = frag / NT;
    const int n = nt * 16 + (lane & 15);
    const int kbase = kc * 32 + (lane >> 4) * 8;
    u16 v[8];
    #pragma unroll
    for (int j = 0; j < 8; ++j)
        v[j] = (n < Ns[e]) ? f2b(W[(size_t)(kbase + j) * Ns[e] + n]) : (u16)0;
    u16* dst = (u16*)P.wws + offs[e] + ((size_t)frag * 64 + lane) * 8;
    *(short8*)dst = *(short8*)v;
}

// ---------------- MFMA helpers: 2 M-tiles over 17 rows, 16 waves ----------------
template <int KT, int NT4>
__device__ __forceinline__ void mfmaAcc(f32x4 acc[2][NT4],
        const u16* __restrict__ act, int ldin,
        const u16* __restrict__ wbase, int NT, int nt0, int ntcnt, int kc0) {
    const int lane = threadIdx.x & 63, wv = threadIdx.x >> 6;
    const int m = lane & 15, quad = lane >> 4;
    const bool v1 = (m < 1);
    for (int kc = 0; kc < KT; ++kc) {
        const int ko = kc * 32 + quad * 8;
        short8 a0 = *(const short8*)(act + m * ldin + ko);
        short8 a1 = {0,0,0,0,0,0,0,0};
        if (v1) a1 = *(const short8*)(act + 16 * ldin + ko);
        #pragma unroll
        for (int i = 0; i < NT4; ++i) {
            const int ntl = wv + NWAVE * i;
            if (ntl < ntcnt) {
                const short8 b = *(const short8*)(wbase +
                    ((size_t)((kc0 + kc) * NT + nt0 + ntl) * 64 + lane) * 8);
                acc[0][i] = __builtin_amdgcn_mfma_f32_16x16x32_bf16(a0, b, acc[0][i], 0, 0, 0);
                acc[1][i] = __builtin_amdgcn_mfma_f32_16x16x32_bf16(a1, b, acc[1][i], 0, 0, 0);
            }
        }
    }
}

// epi(rr, c_rel, val): rr in [0,17) row, c_rel relative to nt0*16.
template <int NT4, class Epi>
__device__ __forceinline__ void mfmaStore(f32x4 acc[2][NT4], int ntcnt, Epi epi) {
    const int lane = threadIdx.x & 63, wv = threadIdx.x >> 6;
    const int col0 = lane & 15, quad = lane >> 4;
    #pragma unroll
    for (int i = 0; i < NT4; ++i) {
        const int ntl = wv + NWAVE * i;
        if (ntl < ntcnt) {
            const int cb = ntl * 16 + col0;
            #pragma unroll
            for (int r = 0; r < 4; ++r) epi(quad * 4 + r, cb, acc[0][i][r]);
            if (quad == 0) epi(16, cb, acc[1][i][0]);
        }
    }
}

template <int KT, int NT4, class Epi>
__device__ __forceinline__ void gemmM(const u16* act, int ldin,
        const u16* wbase, int NT, int nt0, int ntcnt, Epi epi) {
    f32x4 acc[2][NT4];
    #pragma unroll
    for (int mt = 0; mt < 2; ++mt)
        #pragma unroll
        for (int i = 0; i < NT4; ++i) acc[mt][i] = (f32x4){0.f,0.f,0.f,0.f};
    mfmaAcc<KT, NT4>(acc, act, ldin, wbase, NT, nt0, ntcnt, 0);
    mfmaStore<NT4>(acc, ntcnt, epi);
}

// ---------------- main fused kernel: 1 element per block ----------------
__global__ __launch_bounds__(NTHR, 4) void fused_block(Params P) {
    extern __shared__ __align__(16) char smem[];
    float* R   = (float*)(smem + SM_R);    // [17][256] f32
    u16*   AC  = (u16*)  (smem + SM_AC);   // [17][264]
    u16*   T1  = (u16*)  (smem + SM_T1);   // [17][264]
    u16*   W5  = (u16*)  (smem + SM_W5);   // [17][520]
    float* Dbl = (float*)(smem + SM_U);    // [17][24] (mamba only)
    u16*   SC  = (u16*)  (smem + SM_U);    // [8][17][40] (attention only)

    const int tid = threadIdx.x;
    const int lane = tid & 63, wv = tid >> 6;
    const float* __restrict__ xg = P.x + (size_t)blockIdx.x * (LSEQ * 256);
    const u16* __restrict__ ws = P.wws;

    // x -> R (17 rows), non-temporal float4
    for (int i4 = tid; i4 < 17 * 64; i4 += NTHR) {
        int rr = i4 >> 6, d4 = (i4 & 63) * 4;
        f32x4 v = __builtin_nontemporal_load((const f32x4*)(xg + rr * 256 + d4));
        *(f32x4*)(R + rr * RS + d4) = v;
    }
    __syncthreads();

    auto ln17 = [&](auto ld, u16* dst, const float* g, const float* bb) {
        for (int rr = wv; rr < 17; rr += NWAVE) {
            float v[4], s = 0.f, s2 = 0.f;
            #pragma unroll
            for (int j = 0; j < 4; ++j) {
                v[j] = ld(rr, lane + 64 * j);
                s += v[j]; s2 += v[j] * v[j];
            }
            #pragma unroll
            for (int m = 1; m < 64; m <<= 1) {
                s  += __shfl_xor(s, m, 64);
                s2 += __shfl_xor(s2, m, 64);
            }
            float mean = s * (1.0f / 256.0f);
            float var  = s2 * (1.0f / 256.0f) - mean * mean;
            float rstd = rsqrtf(var + 1e-5f);
            #pragma unroll
            for (int j = 0; j < 4; ++j) {
                int d = lane + 64 * j;
                dst[rr * TS + d] = f2b((v[j] - mean) * rstd * g[d] + bb[d]);
            }
        }
    };
    // sparse graph conv (49 nonzeros, compile-time weights), in place;
    // thread owns a full column (race-free)
    auto gconvIP = [&](u16* buf, int stride, int width) {
        if (tid < width) {
            const int d = tid;
            float c[17];
            #pragma unroll
            for (int j = 0; j < 17; ++j) c[j] = b2f(buf[j * stride + d]);
            float o[17];
            o[0]  = 0.25f*c[0] + 0.28867513f*(c[1]+c[4]+c[7]);
            o[1]  = 0.28867513f*c[0] + 0.33333334f*(c[1]+c[2]);
            o[2]  = 0.33333334f*(c[1]+c[2]) + 0.40824829f*c[3];
            o[3]  = 0.40824829f*c[2] + 0.5f*c[3];
            o[4]  = 0.28867513f*c[0] + 0.33333334f*(c[4]+c[5]);
            o[5]  = 0.33333334f*(c[4]+c[5]) + 0.40824829f*c[6];
            o[6]  = 0.40824829f*c[5] + 0.5f*c[6];
            o[7]  = 0.28867513f*c[0] + 0.33333334f*c[7] + 0.25819889f*c[8];
            o[8]  = 0.25819889f*(c[7]+c[9]+c[11]+c[14]) + 0.2f*c[8];
            o[9]  = 0.25819889f*c[8] + 0.33333334f*c[9] + 0.40824829f*c[10];
            o[10] = 0.40824829f*c[9] + 0.5f*c[10];
            o[11] = 0.25819889f*c[8] + 0.33333334f*(c[11]+c[12]);
            o[12] = 0.33333334f*(c[11]+c[12]) + 0.40824829f*c[13];
            o[13] = 0.40824829f*c[12] + 0.5f*c[13];
            o[14] = 0.25819889f*c[8] + 0.33333334f*(c[14]+c[15]);
            o[15] = 0.33333334f*(c[14]+c[15]) + 0.40824829f*c[16];
            o[16] = 0.40824829f*c[15] + 0.5f*c[16];
            #pragma unroll
            for (int i = 0; i < 17; ++i) buf[i * stride + d] = f2b(o[i]);
        }
    };

    // ---------------- GCN ----------------
    ln17([&](int rr, int d) { return R[rr * RS + d]; }, AC, P.gcn_ln_g, P.gcn_ln_b);
    __syncthreads();
    gconvIP(AC, TS, 256);
    __syncthreads();
    gemmM<8, 2>(AC, TS, ws + OFF_GCN_W1, 32, 0, 32,
        [&](int rr, int c, float v) { W5[rr * SS + c] = f2b(gelu_t(v + P.gcn_b1[c])); });
    __syncthreads();
    gconvIP(W5, SS, 512);
    __syncthreads();
    gemmM<16, 1>(W5, SS, ws + OFF_GCN_W2, 16, 0, 16,
        [&](int rr, int c, float v) { R[rr * RS + c] += v + P.gcn_b2[c]; });  // x_a
    __syncthreads();

    // ---------------- Mamba ----------------
    for (int i = tid; i < 17 * 256; i += NTHR) {
        int rr = i >> 8, d = i & 255;
        AC[rr * TS + d] = f2b(R[HOPA[rr] * RS + d] + P.bp_embed[BPEI[rr] * 256 + d]);
    }
    __syncthreads();
    ln17([&](int rr, int d) { return b2f(AC[rr * TS + d]); }, T1, P.ssm_ln_g, P.ssm_ln_b);
    __syncthreads();
    // xm = silu(conv(in_proj[:, :512]))
    gemmM<8, 2>(T1, TS, ws + OFF_INPROJ, 64, 0, 32,
        [&](int rr, int c, float v) { W5[rr * SS + c] = f2b(siluf(v * P.conv_w[c] + P.conv_b[c])); });
    __syncthreads();
    // x_proj (N=24 padded to 32)
    gemmM<16, 1>(W5, SS, ws + OFF_XPROJ, 2, 0, 2,
        [&](int rr, int c, float v) { if (c < 24) Dbl[rr * 24 + c] = v; });
    __syncthreads();
    // selective scan: thread owns channel d (512 indep chains; waves 8-15 idle)
    if (tid < 512) {
        const int d = tid;
        float wdt[16];
        #pragma unroll
        for (int r = 0; r < 16; ++r) wdt[r] = P.dt_proj_w[r * 512 + d];
        const float dtb = P.dt_proj_b[d];
        float Ar[4];
        #pragma unroll
        for (int s = 0; s < 4; ++s) Ar[s] = -__expf(P.A_log[d * 4 + s]);
        const float Dpd = P.Dp[d];
        float h0 = 0.f, h1 = 0.f, h2 = 0.f, h3 = 0.f;
        for (int t = 0; t < LSEQ; ++t) {
            const float* Dv = Dbl + t * 24;
            float a = dtb;
            #pragma unroll
            for (int r = 0; r < 16; ++r) a += Dv[r] * wdt[r];
            float dt_ = softplusf(a);
            float xm = b2f(W5[t * SS + d]);
            float p = dt_ * xm;
            h0 = __expf(dt_ * Ar[0]) * h0 + p * Dv[16];
            h1 = __expf(dt_ * Ar[1]) * h1 + p * Dv[17];
            h2 = __expf(dt_ * Ar[2]) * h2 + p * Dv[18];
            h3 = __expf(dt_ * Ar[3]) * h3 + p * Dv[19];
            float y = h0 * Dv[20] + h1 * Dv[21] + h2 * Dv[22] + h3 * Dv[23] + Dpd * xm;
            W5[t * SS + d] = f2b(y);
        }
    }
    __syncthreads();
    // z half of in_proj; gate y in place
    gemmM<8, 2>(T1, TS, ws + OFF_INPROJ, 64, 32, 32,
        [&](int rr, int c, float v) {
            float y = b2f(W5[rr * SS + c]);
            W5[rr * SS + c] = f2b(y * siluf(v));
        });
    __syncthreads();
    gemmM<16, 1>(W5, SS, ws + OFF_OUTPROJ, 16, 0, 16,
        [&](int rr, int c, float v) { AC[rr * TS + c] = f2b(v); });
    __syncthreads();
    // x_b = 2*x_a + scatter(mamba_out)
    for (int i = tid; i < 17 * 256; i += NTHR) {
        int rr = i >> 8, d = i & 255;
        R[rr * RS + d] = 2.0f * R[rr * RS + d] + b2f(AC[GRAPHA[rr] * TS + d]);
    }
    __syncthreads();

    // ---------------- Attention ----------------
    ln17([&](int rr, int d) { return R[rr * RS + d]; }, AC, P.ln1_g, P.ln1_b);
    __syncthreads();
    // QKV single pass: 48 N-tiles over 16 waves (NT4=3).
    // abs col c: <256 Q -> T1; else K (256-511) | V (512-767) -> W5 col c-256
    gemmM<8, 3>(AC, TS, ws + OFF_QKV, 48, 0, 48,
        [&](int rr, int c, float v) {
            if (c < 256) T1[rr * TS + c] = f2b(v);
            else         W5[rr * SS + (c - 256)] = f2b(v);
        });
    __syncthreads();
    // QK^T via MFMA: wave = (half, head). half 0 -> rows 0-15 tile, half 1 -> row 16.
    // SC zero-padded beyond j=16 (gated ka1 B-frag => exact zeros).
    {
        const int h = wv & 7, half = wv >> 3, m16 = lane & 15, quad = lane >> 4;
        const u16* qb = T1 + h * 32 + quad * 8;
        const u16* kb = W5 + h * 32 + quad * 8;
        short8 ka0 = *(const short8*)(kb + m16 * SS);
        short8 ka1 = {0,0,0,0,0,0,0,0};
        if (m16 == 0) ka1 = *(const short8*)(kb + 16 * SS);
        short8 qa = {0,0,0,0,0,0,0,0};
        if (half == 0)       qa = *(const short8*)(qb + m16 * TS);
        else if (m16 == 0)   qa = *(const short8*)(qb + 16 * TS);
        f32x4 sa = {0.f,0.f,0.f,0.f}, sb = sa;
        sa = __builtin_amdgcn_mfma_f32_16x16x32_bf16(qa, ka0, sa, 0, 0, 0);
        sb = __builtin_amdgcn_mfma_f32_16x16x32_bf16(qa, ka1, sb, 0, 0, 0);
        const float sc = 0.17677669529663687f;
        u16* sh = SC + h * 17 * SCS;
        if (half == 0) {
            #pragma unroll
            for (int r = 0; r < 4; ++r) {
                int i = quad * 4 + r;
                sh[i * SCS + m16]      = f2b(sa[r] * sc);
                sh[i * SCS + 16 + m16] = f2b(sb[r] * sc);
            }
        } else if (quad == 0) {  // row 16 lives in C row 0 of the qa1 tile
            sh[16 * SCS + m16]      = f2b(sa[0] * sc);
            sh[16 * SCS + 16 + m16] = f2b(sb[0] * sc);
        }
    }
    __syncthreads();
    if (tid < 136) {  // 8 heads x 17 rows
        u16* row = SC + tid * SCS;
        float e[17], mx = -3.0e38f, sum = 0.f;
        #pragma unroll
        for (int j = 0; j < 17; ++j) mx = fmaxf(mx, b2f(row[j]));
        #pragma unroll
        for (int j = 0; j < 17; ++j) { e[j] = __expf(b2f(row[j]) - mx); sum += e[j]; }
        float inv = 1.0f / sum;
        #pragma unroll
        for (int j = 0; j < 17; ++j) row[j] = f2b(e[j] * inv);
    }
    __syncthreads();
    // AV via MFMA: wave = (half, head). A = att rows (SC, k-padded zeros),
    // B = V[token k][chan n] from W5 cols 256..511, masked k<17 loads. o -> AC.
    {
        const int h = wv & 7, half = wv >> 3, m16 = lane & 15, quad = lane >> 4;
        const u16* sh = SC + h * 17 * SCS + quad * 8;
        short8 pa = {0,0,0,0,0,0,0,0};
        if (half == 0)       pa = *(const short8*)(sh + m16 * SCS);
        else if (m16 == 0)   pa = *(const short8*)(sh + 16 * SCS);
        #pragma unroll
        for (int nt = 0; nt < 2; ++nt) {
            const u16* vbase = W5 + 256 + h * 32 + nt * 16 + m16;
            short8 vb;
            #pragma unroll
            for (int j = 0; j < 8; ++j) {
                int k = quad * 8 + j;
                vb[j] = (k < 17) ? (short)vbase[k * SS] : (short)0;
            }
            f32x4 o = {0.f,0.f,0.f,0.f};
            o = __builtin_amdgcn_mfma_f32_16x16x32_bf16(pa, vb, o, 0, 0, 0);
            if (half == 0) {
                #pragma unroll
                for (int r = 0; r < 4; ++r) {
                    int i = quad * 4 + r;
                    AC[i * TS + h * 32 + nt * 16 + m16] = f2b(o[r]);
                }
            } else if (quad == 0) {
                AC[16 * TS + h * 32 + nt * 16 + m16] = f2b(o[0]);
            }
        }
    }
    __syncthreads();
    // o' = attn_proj(o) + bias
    gemmM<8, 1>(AC, TS, ws + OFF_ATTNPROJ, 16, 0, 16,
        [&](int rr, int c, float v) { T1[rr * TS + c] = f2b(v + P.attn_proj_b[c]); });
    __syncthreads();

    // ---------------- MLP + final ----------------
    ln17([&](int rr, int d) { return R[rr * RS + d] + b2f(T1[rr * TS + d]); },
         AC, P.ln2_g, P.ln2_b);
    __syncthreads();
    {
        f32x4 accO[2][1];
        #pragma unroll
        for (int mt = 0; mt < 2; ++mt) accO[mt][0] = (f32x4){0.f,0.f,0.f,0.f};
        #pragma unroll
        for (int half = 0; half < 2; ++half) {
            gemmM<8, 2>(AC, TS, ws + OFF_MLP_W1, 64, half * 32, 32,
                [&](int rr, int c, float v) {
                    W5[rr * SS + c] = f2b(gelu_t(v + P.mlp_b1[half * 512 + c]));
                });
            __syncthreads();
            mfmaAcc<16, 1>(accO, W5, SS, ws + OFF_MLP_W2, 16, 0, 16, half * 16);
            __syncthreads();  // W5 reused next half
        }
        float* outg = P.out + (size_t)blockIdx.x * (LSEQ * 256);
        mfmaStore<1>(accO, 16, [&](int rr, int c, float v) {
            float r = v + P.mlp_b2[c] + 2.0f * R[rr * RS + c] + b2f(T1[rr * TS + c]);
            __builtin_nontemporal_store(r, outg + rr * 256 + c);
        });
    }
}

extern "C" void kernel_launch(void* const* d_in, const int* in_sizes, int n_in,
                              void* d_out, int out_size, void* d_ws, size_t ws_size,
                              hipStream_t stream) {
    (void)in_sizes; (void)n_in; (void)ws_size; (void)out_size;
    Params P;
    P.x           = (const float*)d_in[0];
    P.gcn_ln_g    = (const float*)d_in[1];
    P.gcn_ln_b    = (const float*)d_in[2];
    P.gcn_w1      = (const float*)d_in[3];
    P.gcn_b1      = (const float*)d_in[4];
    P.gcn_w2      = (const float*)d_in[5];
    P.gcn_b2      = (const float*)d_in[6];
    P.bp_embed    = (const float*)d_in[7];
    P.ssm_ln_g    = (const float*)d_in[8];
    P.ssm_ln_b    = (const float*)d_in[9];
    P.in_proj_w   = (const float*)d_in[10];
    P.conv_w      = (const float*)d_in[11];
    P.conv_b      = (const float*)d_in[12];
    P.x_proj_w    = (const float*)d_in[13];
    P.dt_proj_w   = (const float*)d_in[14];
    P.dt_proj_b   = (const float*)d_in[15];
    P.A_log       = (const float*)d_in[16];
    P.Dp          = (const float*)d_in[17];
    P.out_proj_w  = (const float*)d_in[18];
    P.ln1_g       = (const float*)d_in[19];
    P.ln1_b       = (const float*)d_in[20];
    P.qkv_w       = (const float*)d_in[21];
    P.attn_proj_w = (const float*)d_in[22];
    P.attn_proj_b = (const float*)d_in[23];
    P.ln2_g       = (const float*)d_in[24];
    P.ln2_b       = (const float*)d_in[25];
    P.mlp_w1      = (const float*)d_in[26];
    P.mlp_b1      = (const float*)d_in[27];
    P.mlp_w2      = (const float*)d_in[28];
    P.mlp_b2      = (const float*)d_in[29];
    P.wws         = (const u16*)d_ws;
    P.out         = (float*)d_out;
    static int smem_set = 0;
    if (!smem_set) {
        hipFuncSetAttribute(reinterpret_cast<const void*>(fused_block),
                            hipFuncAttributeMaxDynamicSharedMemorySize, SMEM_BYTES);
        smem_set = 1;
    }
    hipLaunchKernelGGL(prepack, dim3(712), dim3(256), 0, stream, P);
    hipLaunchKernelGGL(fused_block, dim3(4096), dim3(NTHR), SMEM_BYTES, stream, P);
}